// Round 3
// baseline (179.582 us; speedup 1.0000x reference)
//
#include <hip/hip_runtime.h>
#include <math.h>

#define N_ATOMS 4096
#define SPECIES 100
#define FEA 64
#define M_NBR 12

typedef unsigned short u16;
typedef __attribute__((ext_vector_type(8))) short bf16x8;
typedef __attribute__((ext_vector_type(4))) float f32x4;

constexpr float LN_EPS = 1e-5f;
constexpr float GAUSS_COEFF = -31.0078125f; // -0.5/(8/63)^2
constexpr float D2_INF = 3.4e38f;

__device__ __forceinline__ float sigmoidf_(float x){ return 1.0f/(1.0f+__expf(-x)); }
__device__ __forceinline__ float softplusf_(float x){
    return fmaxf(x, 0.0f) + log1pf(__expf(-fabsf(x)));
}
// split f32 into bf16 hi + bf16 lo (round-to-nearest-even)
__device__ __forceinline__ void split_bf16(float x, u16& h, u16& l){
    unsigned u = __float_as_uint(x);
    unsigned hr = (u + 0x7FFFu + ((u >> 16) & 1u)) >> 16;
    h = (u16)hr;
    float hf = __uint_as_float(hr << 16);
    float lo = x - hf;
    unsigned u2 = __float_as_uint(lo);
    l = (u16)((u2 + 0x7FFFu + ((u2 >> 16) & 1u)) >> 16);
}

// ---------------- fracs transpose: [N,3] -> fx,fy,fz ----------------
__global__ __launch_bounds__(256) void k_prep(const float* __restrict__ fracs,
        float* __restrict__ fx, float* __restrict__ fy, float* __restrict__ fz){
    int j = blockIdx.x * 256 + threadIdx.x;
    fx[j] = fracs[j*3+0];
    fy[j] = fracs[j*3+1];
    fz[j] = fracs[j*3+2];
}

// ---------------- weight prep: W[192][128] f32 -> W^T[128][192] bf16 hi/lo ----------------
__global__ __launch_bounds__(256) void k_prepw(const float* __restrict__ w1,
        const float* __restrict__ w2, u16* __restrict__ wt1h, u16* __restrict__ wt1l,
        u16* __restrict__ wt2h, u16* __restrict__ wt2l){
    int gid = blockIdx.x * 256 + threadIdx.x;      // 0..49151
    int layer = gid / 24576;
    int e = gid % 24576;
    int k = e >> 7, n = e & 127;
    const float* w = layer ? w2 : w1;
    float x = w[e];
    u16 h, l; split_bf16(x, h, l);
    u16* th = layer ? wt2h : wt1h;
    u16* tl = layer ? wt2l : wt1l;
    th[n * 192 + k] = h;
    tl[n * 192 + k] = l;
}

// ---------------- embedding: softmax(species_logits) @ emb_w + emb_b ----------------
__global__ __launch_bounds__(256) void k_embed(const float* __restrict__ logits,
        const float* __restrict__ emb_w, const float* __restrict__ emb_b,
        float* __restrict__ atom0, u16* __restrict__ a0h, u16* __restrict__ a0l){
    __shared__ float sE[4][SPECIES];
    int tid = threadIdx.x;
    int grp = tid >> 6;
    int f = tid & 63;
    int a = blockIdx.x * 4 + grp;
    const float* lg = logits + (long)a * SPECIES;
    float l0 = lg[f];
    float l1 = (f + 64 < SPECIES) ? lg[f + 64] : -1e30f;
    float mx = fmaxf(l0, l1);
    #pragma unroll
    for (int off = 32; off; off >>= 1) mx = fmaxf(mx, __shfl_xor(mx, off));
    float e0 = __expf(l0 - mx);
    float e1 = (f + 64 < SPECIES) ? __expf(l1 - mx) : 0.0f;
    sE[grp][f] = e0;
    if (f + 64 < SPECIES) sE[grp][64 + f] = e1;
    float sm = e0 + e1;
    #pragma unroll
    for (int off = 32; off; off >>= 1) sm += __shfl_xor(sm, off);
    __syncthreads();
    float acc = 0.0f;
    for (int s = 0; s < SPECIES; ++s) acc += sE[grp][s] * emb_w[s * FEA + f];
    float v = acc / sm + emb_b[f];
    atom0[(long)a * FEA + f] = v;
    u16 h, lo; split_bf16(v, h, lo);
    a0h[a * FEA + f] = h;
    a0l[a * FEA + f] = lo;
}

// ---------------- pairwise min-image distances + top-12, register-resident ----------------
__global__ __launch_bounds__(256) void k_topk(const float* __restrict__ fx,
        const float* __restrict__ fy, const float* __restrict__ fz,
        const float* __restrict__ lat, int* __restrict__ nbr_idx,
        float* __restrict__ nbr_dist){
    __shared__ float sWv[4];
    __shared__ int   sWi[4];
    int i = blockIdx.x, tid = threadIdx.x;
    int lane = tid & 63, wid = tid >> 6;
    float l00=lat[0],l01=lat[1],l02=lat[2];
    float l10=lat[3],l11=lat[4],l12=lat[5];
    float l20=lat[6],l21=lat[7],l22=lat[8];
    float xi = fx[i], yi = fy[i], zi = fz[i];
    float d2r[16];
    #pragma unroll
    for (int k = 0; k < 16; ++k){
        int j = tid + k * 256;
        float dx = xi - fx[j];
        float dy = yi - fy[j];
        float dz = zi - fz[j];
        dx -= rintf(dx); dy -= rintf(dy); dz -= rintf(dz);
        float cx = dx*l00 + dy*l10 + dz*l20;
        float cy = dx*l01 + dy*l11 + dz*l21;
        float cz = dx*l02 + dy*l12 + dz*l22;
        float d2 = cx*cx + cy*cy + cz*cz;
        d2r[k] = (j == i) ? D2_INF : d2;
    }
    for (int r = 0; r < M_NBR; ++r){
        float v = D2_INF; int id = N_ATOMS;
        #pragma unroll
        for (int k = 0; k < 16; ++k){
            int j = tid + k * 256;
            float x = d2r[k];
            if (x < v || (x == v && j < id)){ v = x; id = j; }
        }
        #pragma unroll
        for (int off = 32; off; off >>= 1){
            float ov = __shfl_down(v, off);
            int   oi = __shfl_down(id, off);
            if (ov < v || (ov == v && oi < id)){ v = ov; id = oi; }
        }
        if (lane == 0){ sWv[wid] = v; sWi[wid] = id; }
        __syncthreads();
        float bv = sWv[0]; int bi = sWi[0];
        #pragma unroll
        for (int w2 = 1; w2 < 4; ++w2){
            float wv = sWv[w2]; int wi = sWi[w2];
            if (wv < bv || (wv == bv && wi < bi)){ bv = wv; bi = wi; }
        }
        if (tid == (bi & 255)) d2r[bi >> 8] = D2_INF;   // invalidate winner in its owner's regs
        if (tid == 0){
            nbr_idx[i * M_NBR + r]  = bi;
            nbr_dist[i * M_NBR + r] = sqrtf(bv);
        }
        __syncthreads();
    }
}

// ---------------- CGCNN conv layer via MFMA (bf16 hi/lo error compensation) ----------------
// 8 atoms/block (96 rows = 6 M-tiles), 3 waves x 2 M-tiles x 8 N-tiles, K=192 in 6 chunks.
// Grid = 512 -> 2 blocks/CU, 6 waves/CU.
__global__ __launch_bounds__(192) void k_layer(
        const float* __restrict__ selfF,
        const u16* __restrict__ selfH, const u16* __restrict__ selfL,
        const u16* __restrict__ nbrH,  const u16* __restrict__ nbrL,
        const int* __restrict__ nbr_idx, const float* __restrict__ nbr_dist,
        const u16* __restrict__ wth, const u16* __restrict__ wtl,
        const float* __restrict__ bias, const float* __restrict__ gg,
        const float* __restrict__ bb,
        float* __restrict__ outF, u16* __restrict__ outH, u16* __restrict__ outL)
{
    __shared__ float prod[96][68];
    const int t = threadIdx.x;
    const int w = t >> 6, l = t & 63;
    const int lg = l >> 4, lr = l & 15;
    const int blk = blockIdx.x;
    const int rbase = blk * 96 + w * 32;

    int aidx[2], nidx[2];
    float dist[2];
    #pragma unroll
    for (int mt = 0; mt < 2; ++mt){
        int r = rbase + mt * 16 + lr;
        aidx[mt] = r / 12;
        nidx[mt] = nbr_idx[r];
        dist[mt] = nbr_dist[r];
    }
    float bv[8], gv[8], bev[8];
    #pragma unroll
    for (int nt = 0; nt < 8; ++nt){
        int c = nt * 16 + lr;
        bv[nt] = bias[c]; gv[nt] = gg[c]; bev[nt] = bb[c];
    }

    f32x4 acc[2][8];
    #pragma unroll
    for (int mt = 0; mt < 2; ++mt)
        #pragma unroll
        for (int nt = 0; nt < 8; ++nt) acc[mt][nt] = 0.0f;

    #pragma unroll
    for (int ch = 0; ch < 6; ++ch){
        bf16x8 ah[2], al[2];
        if (ch < 2){
            #pragma unroll
            for (int mt = 0; mt < 2; ++mt){
                int o = aidx[mt] * 64 + ch * 32 + lg * 8;
                ah[mt] = *(const bf16x8*)(selfH + o);
                al[mt] = *(const bf16x8*)(selfL + o);
            }
        } else if (ch < 4){
            #pragma unroll
            for (int mt = 0; mt < 2; ++mt){
                int o = nidx[mt] * 64 + (ch - 2) * 32 + lg * 8;
                ah[mt] = *(const bf16x8*)(nbrH + o);
                al[mt] = *(const bf16x8*)(nbrL + o);
            }
        } else {
            #pragma unroll
            for (int mt = 0; mt < 2; ++mt){
                float d = dist[mt];
                bf16x8 vh, vl;
                #pragma unroll
                for (int i = 0; i < 8; ++i){
                    int k = (ch - 4) * 32 + lg * 8 + i;
                    float off = (float)k * (8.0f / 63.0f);
                    float dd = d - off;
                    float v = __expf(GAUSS_COEFF * dd * dd);
                    u16 hh, ll; split_bf16(v, hh, ll);
                    vh[i] = (short)hh; vl[i] = (short)ll;
                }
                ah[mt] = vh; al[mt] = vl;
            }
        }
        #pragma unroll
        for (int nt = 0; nt < 8; ++nt){
            int wo = (nt * 16 + lr) * 192 + ch * 32 + lg * 8;
            bf16x8 bh = *(const bf16x8*)(wth + wo);
            bf16x8 bl = *(const bf16x8*)(wtl + wo);
            #pragma unroll
            for (int mt = 0; mt < 2; ++mt){
                acc[mt][nt] = __builtin_amdgcn_mfma_f32_16x16x32_bf16(al[mt], bh, acc[mt][nt], 0, 0, 0);
                acc[mt][nt] = __builtin_amdgcn_mfma_f32_16x16x32_bf16(ah[mt], bl, acc[mt][nt], 0, 0, 0);
                acc[mt][nt] = __builtin_amdgcn_mfma_f32_16x16x32_bf16(ah[mt], bh, acc[mt][nt], 0, 0, 0);
            }
        }
    }

    // LayerNorm per row (128 cols) + sigmoid*softplus, in registers.
    // C layout: row_in_tile = lg*4 + r, col = nt*16 + lr -> each row lives in one 16-lane group.
    #pragma unroll
    for (int mt = 0; mt < 2; ++mt){
        float z[8][4];
        float s[4] = {0,0,0,0}, q[4] = {0,0,0,0};
        #pragma unroll
        for (int nt = 0; nt < 8; ++nt)
            #pragma unroll
            for (int r = 0; r < 4; ++r){
                float v = acc[mt][nt][r] + bv[nt];
                z[nt][r] = v;
                s[r] += v; q[r] += v * v;
            }
        #pragma unroll
        for (int r = 0; r < 4; ++r){
            #pragma unroll
            for (int m = 1; m < 16; m <<= 1){
                s[r] += __shfl_xor(s[r], m);
                q[r] += __shfl_xor(q[r], m);
            }
        }
        float mean[4], inv[4];
        #pragma unroll
        for (int r = 0; r < 4; ++r){
            mean[r] = s[r] * (1.0f / 128.0f);
            float var = q[r] * (1.0f / 128.0f) - mean[r] * mean[r];
            inv[r] = rsqrtf(var + LN_EPS);
        }
        #pragma unroll
        for (int nt = 0; nt < 4; ++nt)
            #pragma unroll
            for (int r = 0; r < 4; ++r){
                float zf = (z[nt][r]     - mean[r]) * inv[r] * gv[nt]     + bev[nt];
                float zc = (z[nt + 4][r] - mean[r]) * inv[r] * gv[nt + 4] + bev[nt + 4];
                float p = sigmoidf_(zf) * softplusf_(zc);
                prod[w * 32 + mt * 16 + lg * 4 + r][nt * 16 + lr] = p;
            }
    }
    __syncthreads();

    // per-atom reduction over 12 neighbor rows + residual + softplus
    if (t < 128){
        int a_loc = t >> 4;            // 0..7
        int c0 = (t & 15) * 4;         // 4 consecutive channels
        float4 sm = make_float4(0, 0, 0, 0);
        #pragma unroll
        for (int m = 0; m < 12; ++m){
            const float4 pv = *(const float4*)&prod[a_loc * 12 + m][c0];
            sm.x += pv.x; sm.y += pv.y; sm.z += pv.z; sm.w += pv.w;
        }
        int atom = blk * 8 + a_loc;
        const float4 sf = *(const float4*)(selfF + (long)atom * 64 + c0);
        float o[4];
        o[0] = softplusf_(sf.x + sm.x);
        o[1] = softplusf_(sf.y + sm.y);
        o[2] = softplusf_(sf.z + sm.z);
        o[3] = softplusf_(sf.w + sm.w);
        *(float4*)(outF + (long)atom * 64 + c0) = make_float4(o[0], o[1], o[2], o[3]);
        u16 h0,l0,h1,l1,h2,l2,h3,l3;
        split_bf16(o[0], h0, l0); split_bf16(o[1], h1, l1);
        split_bf16(o[2], h2, l2); split_bf16(o[3], h3, l3);
        ushort4 hv; hv.x=h0; hv.y=h1; hv.z=h2; hv.w=h3;
        ushort4 lv; lv.x=l0; lv.y=l1; lv.z=l2; lv.w=l3;
        *(ushort4*)(outH + atom * 64 + c0) = hv;
        *(ushort4*)(outL + atom * 64 + c0) = lv;
    }
}

// ---------------- pooling: deterministic two-stage tree ----------------
__global__ __launch_bounds__(256) void k_partial(const float* __restrict__ atom,
        const float* __restrict__ occ, float* __restrict__ partials){
    int b = blockIdx.x, tid = threadIdx.x;
    int f = tid & 63, sub = tid >> 6;
    __shared__ float sAcc[256];
    float acc = 0.0f;
    for (int it = 0; it < 16; ++it){
        int a = b * 64 + sub + it * 4;
        float p = sigmoidf_(occ[a]);
        acc += atom[(long)a * FEA + f] * p;
    }
    sAcc[tid] = acc;
    __syncthreads();
    if (tid < 64){
        float s = sAcc[f] + sAcc[64 + f] + sAcc[128 + f] + sAcc[192 + f];
        partials[b * 65 + f] = s;
        float po = sigmoidf_(occ[b * 64 + f]);
        #pragma unroll
        for (int off = 32; off; off >>= 1) po += __shfl_down(po, off);
        if (f == 0) partials[b * 65 + 64] = po;
    }
}

__global__ __launch_bounds__(64) void k_final(const float* __restrict__ partials,
        const float* __restrict__ fc_w, const float* __restrict__ fc_b,
        float* __restrict__ out){
    int f = threadIdx.x;
    float num = 0.0f;
    for (int p = 0; p < 64; ++p) num += partials[p * 65 + f];
    float occs = partials[f * 65 + 64];
    #pragma unroll
    for (int off = 32; off; off >>= 1) occs += __shfl_down(occs, off);
    occs = __shfl(occs, 0);
    float gf = num / (occs + 1e-6f);
    float v = gf * fc_w[f];
    #pragma unroll
    for (int off = 32; off; off >>= 1) v += __shfl_down(v, off);
    if (f == 0) out[0] = v + fc_b[0];
}

extern "C" void kernel_launch(void* const* d_in, const int* in_sizes, int n_in,
                              void* d_out, int out_size, void* d_ws, size_t ws_size,
                              hipStream_t stream) {
    const float* lat    = (const float*)d_in[0];
    const float* fracs  = (const float*)d_in[1];
    const float* slog   = (const float*)d_in[2];
    const float* occ    = (const float*)d_in[3];
    const float* emb_w  = (const float*)d_in[4];
    const float* emb_b  = (const float*)d_in[5];
    const float* w1     = (const float*)d_in[6];
    const float* b1     = (const float*)d_in[7];
    const float* g1     = (const float*)d_in[8];
    const float* be1    = (const float*)d_in[9];
    const float* w2     = (const float*)d_in[10];
    const float* b2     = (const float*)d_in[11];
    const float* g2     = (const float*)d_in[12];
    const float* be2    = (const float*)d_in[13];
    const float* fc_w   = (const float*)d_in[14];
    const float* fc_b   = (const float*)d_in[15];
    float* out = (float*)d_out;

    char* ws = (char*)d_ws;
    auto alloc = [&](size_t bytes) -> void* {
        void* p = (void*)ws;
        ws += (bytes + 255) & ~(size_t)255;
        return p;
    };
    int*   nbr_idx  = (int*)  alloc((size_t)N_ATOMS * M_NBR * 4);
    float* nbr_dist = (float*)alloc((size_t)N_ATOMS * M_NBR * 4);
    float* atom0    = (float*)alloc((size_t)N_ATOMS * FEA * 4);
    float* atom1    = (float*)alloc((size_t)N_ATOMS * FEA * 4);
    u16*   a0h      = (u16*)  alloc((size_t)N_ATOMS * FEA * 2);
    u16*   a0l      = (u16*)  alloc((size_t)N_ATOMS * FEA * 2);
    u16*   a1h      = (u16*)  alloc((size_t)N_ATOMS * FEA * 2);
    u16*   a1l      = (u16*)  alloc((size_t)N_ATOMS * FEA * 2);
    u16*   wt1h     = (u16*)  alloc((size_t)192 * 128 * 2);
    u16*   wt1l     = (u16*)  alloc((size_t)192 * 128 * 2);
    u16*   wt2h     = (u16*)  alloc((size_t)192 * 128 * 2);
    u16*   wt2l     = (u16*)  alloc((size_t)192 * 128 * 2);
    float* fxa      = (float*)alloc((size_t)N_ATOMS * 4);
    float* fya      = (float*)alloc((size_t)N_ATOMS * 4);
    float* fza      = (float*)alloc((size_t)N_ATOMS * 4);
    float* partials = (float*)alloc((size_t)64 * 65 * 4);

    k_prep   <<<N_ATOMS / 256, 256, 0, stream>>>(fracs, fxa, fya, fza);
    k_prepw  <<<192, 256, 0, stream>>>(w1, w2, wt1h, wt1l, wt2h, wt2l);
    k_embed  <<<N_ATOMS / 4, 256, 0, stream>>>(slog, emb_w, emb_b, atom0, a0h, a0l);
    k_topk   <<<N_ATOMS, 256, 0, stream>>>(fxa, fya, fza, lat, nbr_idx, nbr_dist);
    k_layer  <<<N_ATOMS / 8, 192, 0, stream>>>(atom0, a0h, a0l, a0h, a0l,
                nbr_idx, nbr_dist, wt1h, wt1l, b1, g1, be1, atom1, a1h, a1l);
    k_layer  <<<N_ATOMS / 8, 192, 0, stream>>>(atom1, a1h, a1l, a0h, a0l,
                nbr_idx, nbr_dist, wt2h, wt2l, b2, g2, be2, atom1, a1h, a1l);
    k_partial<<<64, 256, 0, stream>>>(atom1, occ, partials);
    k_final  <<<1, 64, 0, stream>>>(partials, fc_w, fc_b, out);
}

// Round 4
// 122.423 us; speedup vs baseline: 1.4669x; 1.4669x over previous
//
#include <hip/hip_runtime.h>
#include <math.h>

#define N_ATOMS 4096
#define SPECIES 100
#define FEA 64
#define M_NBR 12
#define BA 4   // atoms per k_layer block

typedef unsigned short u16;
typedef __attribute__((ext_vector_type(8))) short bf16x8;
typedef __attribute__((ext_vector_type(4))) float f32x4;

constexpr float LN_EPS = 1e-5f;
constexpr float GAUSS_COEFF = -31.0078125f; // -0.5/(8/63)^2
constexpr float D2_INF = 3.4e38f;

__device__ __forceinline__ float sigmoidf_(float x){ return 1.0f/(1.0f+__expf(-x)); }
__device__ __forceinline__ float softplusf_(float x){
    return fmaxf(x, 0.0f) + log1pf(__expf(-fabsf(x)));
}
// split f32 into bf16 hi + bf16 lo (round-to-nearest-even)
__device__ __forceinline__ void split_bf16(float x, u16& h, u16& l){
    unsigned u = __float_as_uint(x);
    unsigned hr = (u + 0x7FFFu + ((u >> 16) & 1u)) >> 16;
    h = (u16)hr;
    float hf = __uint_as_float(hr << 16);
    float lo = x - hf;
    unsigned u2 = __float_as_uint(lo);
    l = (u16)((u2 + 0x7FFFu + ((u2 >> 16) & 1u)) >> 16);
}

// ---------------- fracs transpose: [N,3] -> fx,fy,fz ----------------
__global__ __launch_bounds__(256) void k_prep(const float* __restrict__ fracs,
        float* __restrict__ fx, float* __restrict__ fy, float* __restrict__ fz){
    int j = blockIdx.x * 256 + threadIdx.x;
    fx[j] = fracs[j*3+0];
    fy[j] = fracs[j*3+1];
    fz[j] = fracs[j*3+2];
}

// ---------------- weight prep: W[192][128] f32 -> wave-coalesced bf16 hi/lo ----------------
// dest layout: [(ch*8 + nt)*64 + lane]*8 + i  where lane=lg*16+lr,
// element = W^T[n = nt*16+lr][k = ch*32 + lg*8 + i]  (contiguous 1KB per (ch,nt) per wave)
__global__ __launch_bounds__(256) void k_prepw(const float* __restrict__ w1,
        const float* __restrict__ w2, u16* __restrict__ wt1h, u16* __restrict__ wt1l,
        u16* __restrict__ wt2h, u16* __restrict__ wt2l){
    int gid = blockIdx.x * 256 + threadIdx.x;      // 0..49151
    int layer = gid / 24576;
    int e = gid % 24576;
    int k = e >> 7, n = e & 127;
    const float* w = layer ? w2 : w1;
    float x = w[e];
    u16 h, l; split_bf16(x, h, l);
    int ch = k >> 5, lg = (k >> 3) & 3, i = k & 7;
    int nt = n >> 4, lr = n & 15;
    int lane = lg * 16 + lr;
    int dest = ((ch * 8 + nt) * 64 + lane) * 8 + i;
    u16* th = layer ? wt2h : wt1h;
    u16* tl = layer ? wt2l : wt1l;
    th[dest] = h;
    tl[dest] = l;
}

// ---------------- embedding: softmax(species_logits) @ emb_w + emb_b ----------------
__global__ __launch_bounds__(256) void k_embed(const float* __restrict__ logits,
        const float* __restrict__ emb_w, const float* __restrict__ emb_b,
        float* __restrict__ atom0, u16* __restrict__ a0h, u16* __restrict__ a0l){
    __shared__ float sE[4][SPECIES];
    int tid = threadIdx.x;
    int grp = tid >> 6;
    int f = tid & 63;
    int a = blockIdx.x * 4 + grp;
    const float* lg = logits + (long)a * SPECIES;
    float l0 = lg[f];
    float l1 = (f + 64 < SPECIES) ? lg[f + 64] : -1e30f;
    float mx = fmaxf(l0, l1);
    #pragma unroll
    for (int off = 32; off; off >>= 1) mx = fmaxf(mx, __shfl_xor(mx, off));
    float e0 = __expf(l0 - mx);
    float e1 = (f + 64 < SPECIES) ? __expf(l1 - mx) : 0.0f;
    sE[grp][f] = e0;
    if (f + 64 < SPECIES) sE[grp][64 + f] = e1;
    float sm = e0 + e1;
    #pragma unroll
    for (int off = 32; off; off >>= 1) sm += __shfl_xor(sm, off);
    __syncthreads();
    float acc = 0.0f;
    for (int s = 0; s < SPECIES; ++s) acc += sE[grp][s] * emb_w[s * FEA + f];
    float v = acc / sm + emb_b[f];
    atom0[(long)a * FEA + f] = v;
    u16 h, lo; split_bf16(v, h, lo);
    a0h[a * FEA + f] = h;
    a0l[a * FEA + f] = lo;
}

// ---------------- top-12 via histogram threshold + candidate compaction ----------------
__global__ __launch_bounds__(256) void k_topk(const float* __restrict__ fx,
        const float* __restrict__ fy, const float* __restrict__ fz,
        const float* __restrict__ lat, int* __restrict__ nbr_idx,
        float* __restrict__ nbr_dist){
    __shared__ int   hist[256];
    __shared__ int   cnt;
    __shared__ float sThr;
    __shared__ float candD[256];
    __shared__ int   candI[256];
    int i = blockIdx.x, tid = threadIdx.x;
    hist[tid] = 0;
    if (tid == 0) cnt = 0;
    __syncthreads();
    float l00=lat[0],l01=lat[1],l02=lat[2];
    float l10=lat[3],l11=lat[4],l12=lat[5];
    float l20=lat[6],l21=lat[7],l22=lat[8];
    float xi = fx[i], yi = fy[i], zi = fz[i];
    float d2r[16];
    #pragma unroll
    for (int k = 0; k < 16; ++k){
        int j = tid + k * 256;
        float dx = xi - fx[j];
        float dy = yi - fy[j];
        float dz = zi - fz[j];
        dx -= rintf(dx); dy -= rintf(dy); dz -= rintf(dz);
        float cx = dx*l00 + dy*l10 + dz*l20;
        float cy = dx*l01 + dy*l11 + dz*l21;
        float cz = dx*l02 + dy*l12 + dz*l22;
        float d2 = cx*cx + cy*cy + cz*cz;
        if (j == i) d2 = D2_INF;
        d2r[k] = d2;
        if (d2 < 4.0f) atomicAdd(&hist[(int)(d2 * 64.0f)], 1);
    }
    __syncthreads();
    // wave 0: prefix over 64 groups of 4 bins, find threshold bin containing 12th smallest
    if (tid < 64){
        int s0 = hist[4*tid] + hist[4*tid+1] + hist[4*tid+2] + hist[4*tid+3];
        int sc = s0;
        #pragma unroll
        for (int off = 1; off < 64; off <<= 1){
            int o = __shfl_up(sc, off);
            if (tid >= off) sc += o;
        }
        unsigned long long mball = __ballot(sc >= M_NBR);
        if (mball == 0ULL){
            if (tid == 0) sThr = 1e30f;   // degenerate fallback (never hit at this density)
        } else {
            int gbin = __ffsll(mball) - 1;
            if (tid == gbin){
                int c = sc - s0;
                float th = 4.0f;
                #pragma unroll
                for (int b = 0; b < 4; ++b){
                    c += hist[4*gbin + b];
                    if (c >= M_NBR){ th = (float)(4*gbin + b + 1) * (1.0f/64.0f); break; }
                }
                sThr = th;
            }
        }
    }
    __syncthreads();
    float thr = sThr;
    #pragma unroll
    for (int k = 0; k < 16; ++k){
        if (d2r[k] < thr){
            int p = atomicAdd(&cnt, 1);
            if (p < 256){ candD[p] = d2r[k]; candI[p] = tid + k * 256; }
        }
    }
    __syncthreads();
    // wave 0: 12 deterministic argmin rounds over candidates (tie-break lower index)
    if (tid < 64){
        int n = cnt < 256 ? cnt : 256;
        float v0 = (tid       < n) ? candD[tid]       : D2_INF;
        int   i0 = (tid       < n) ? candI[tid]       : 0x7FFFFFFF;
        float v1 = (tid + 64  < n) ? candD[tid + 64]  : D2_INF;
        int   i1 = (tid + 64  < n) ? candI[tid + 64]  : 0x7FFFFFFF;
        float v2 = (tid + 128 < n) ? candD[tid + 128] : D2_INF;
        int   i2 = (tid + 128 < n) ? candI[tid + 128] : 0x7FFFFFFF;
        float v3 = (tid + 192 < n) ? candD[tid + 192] : D2_INF;
        int   i3 = (tid + 192 < n) ? candI[tid + 192] : 0x7FFFFFFF;
        for (int r = 0; r < M_NBR; ++r){
            float bv = v0; int bi = i0;
            if (v1 < bv || (v1 == bv && i1 < bi)){ bv = v1; bi = i1; }
            if (v2 < bv || (v2 == bv && i2 < bi)){ bv = v2; bi = i2; }
            if (v3 < bv || (v3 == bv && i3 < bi)){ bv = v3; bi = i3; }
            #pragma unroll
            for (int off = 1; off < 64; off <<= 1){
                float ov = __shfl_xor(bv, off);
                int   oi = __shfl_xor(bi, off);
                if (ov < bv || (ov == bv && oi < bi)){ bv = ov; bi = oi; }
            }
            if (i0 == bi) v0 = D2_INF;
            if (i1 == bi) v1 = D2_INF;
            if (i2 == bi) v2 = D2_INF;
            if (i3 == bi) v3 = D2_INF;
            if (tid == 0){
                nbr_idx[i * M_NBR + r]  = bi;
                nbr_dist[i * M_NBR + r] = sqrtf(bv);
            }
        }
    }
}

// ---------------- fused CGCNN layers 1+2 via MFMA (bf16 hi/lo compensation) ----------------
// 4 atoms/block (48 rows), 3 waves x 1 M-tile x 8 N-tiles, K=192 in 6 chunks of 32.
// Layer 2 self features come from layer 1's in-block epilogue via LDS; neighbor features
// are the original embedding for BOTH layers (fragments kept in registers).
__global__ __launch_bounds__(192) void k_layer2(
        const float* __restrict__ atom0F,
        const u16* __restrict__ a0h, const u16* __restrict__ a0l,
        const int* __restrict__ nbr_idx, const float* __restrict__ nbr_dist,
        const u16* __restrict__ w1h, const u16* __restrict__ w1l,
        const float* __restrict__ b1, const float* __restrict__ g1, const float* __restrict__ be1,
        const u16* __restrict__ w2h, const u16* __restrict__ w2l,
        const float* __restrict__ b2, const float* __restrict__ g2, const float* __restrict__ be2,
        float* __restrict__ outF)
{
    __shared__ float prod[48][68];
    __shared__ float sSF[BA][64];
    __shared__ u16   sSH[BA][64];
    __shared__ u16   sSL[BA][64];
    const int t = threadIdx.x;
    const int w = t / 64, l = t & 63;
    const int lg = l >> 4, lr = l & 15;
    const int blk = blockIdx.x;
    const int r = blk * 48 + w * 16 + lr;        // global neighbor-row
    const int aload = r / 12;                    // global atom of this row
    const int aloc = (w * 16 + lr) / 12;         // local atom 0..3
    const int nid = nbr_idx[r];
    const float dist = nbr_dist[r];

    // gaussian fragments (chunks 4,5) in registers, shared by both layers
    bf16x8 gh[2], gl[2];
    #pragma unroll
    for (int c = 0; c < 2; ++c){
        #pragma unroll
        for (int i = 0; i < 8; ++i){
            int k = c * 32 + lg * 8 + i;
            float off = (float)k * (8.0f / 63.0f);
            float dd = dist - off;
            float v = __expf(GAUSS_COEFF * dd * dd);
            u16 hh, ll; split_bf16(v, hh, ll);
            gh[c][i] = (short)hh; gl[c][i] = (short)ll;
        }
    }
    // neighbor fragments (chunks 2,3) in registers, shared by both layers
    bf16x8 nh[2], nl[2];
    #pragma unroll
    for (int c = 0; c < 2; ++c){
        int o = nid * 64 + c * 32 + lg * 8;
        nh[c] = *(const bf16x8*)(a0h + o);
        nl[c] = *(const bf16x8*)(a0l + o);
    }

    for (int layer = 0; layer < 2; ++layer){
        const u16* wh   = layer ? w2h : w1h;
        const u16* wl   = layer ? w2l : w1l;
        const float* bias = layer ? b2 : b1;
        const float* gga  = layer ? g2 : g1;
        const float* bba  = layer ? be2 : be1;

        // self fragments (chunks 0,1)
        bf16x8 sh[2], sl[2];
        if (layer == 0){
            #pragma unroll
            for (int c = 0; c < 2; ++c){
                int o = aload * 64 + c * 32 + lg * 8;
                sh[c] = *(const bf16x8*)(a0h + o);
                sl[c] = *(const bf16x8*)(a0l + o);
            }
        } else {
            #pragma unroll
            for (int c = 0; c < 2; ++c){
                sh[c] = *(const bf16x8*)(&sSH[aloc][c * 32 + lg * 8]);
                sl[c] = *(const bf16x8*)(&sSL[aloc][c * 32 + lg * 8]);
            }
        }

        float bv[8], gv[8], bev[8];
        #pragma unroll
        for (int nt = 0; nt < 8; ++nt){
            int c = nt * 16 + lr;
            bv[nt] = bias[c]; gv[nt] = gga[c]; bev[nt] = bba[c];
        }

        f32x4 acc[8];
        #pragma unroll
        for (int nt = 0; nt < 8; ++nt) acc[nt] = 0.0f;

        #pragma unroll
        for (int ch = 0; ch < 6; ++ch){
            bf16x8 ah = (ch < 2) ? sh[ch] : (ch < 4) ? nh[ch - 2] : gh[ch - 4];
            bf16x8 al = (ch < 2) ? sl[ch] : (ch < 4) ? nl[ch - 2] : gl[ch - 4];
            #pragma unroll
            for (int nt = 0; nt < 8; ++nt){
                const bf16x8 bh = *(const bf16x8*)(wh + ((ch * 8 + nt) * 64 + l) * 8);
                const bf16x8 blo = *(const bf16x8*)(wl + ((ch * 8 + nt) * 64 + l) * 8);
                acc[nt] = __builtin_amdgcn_mfma_f32_16x16x32_bf16(al, bh,  acc[nt], 0, 0, 0);
                acc[nt] = __builtin_amdgcn_mfma_f32_16x16x32_bf16(ah, blo, acc[nt], 0, 0, 0);
                acc[nt] = __builtin_amdgcn_mfma_f32_16x16x32_bf16(ah, bh,  acc[nt], 0, 0, 0);
            }
        }

        // LayerNorm per row over 128 cols, in registers (row = lg*4+rr lives in one 16-lane group)
        {
            float z[8][4];
            float s[4] = {0,0,0,0}, q[4] = {0,0,0,0};
            #pragma unroll
            for (int nt = 0; nt < 8; ++nt)
                #pragma unroll
                for (int rr = 0; rr < 4; ++rr){
                    float v = acc[nt][rr] + bv[nt];
                    z[nt][rr] = v;
                    s[rr] += v; q[rr] += v * v;
                }
            #pragma unroll
            for (int rr = 0; rr < 4; ++rr){
                #pragma unroll
                for (int m = 1; m < 16; m <<= 1){
                    s[rr] += __shfl_xor(s[rr], m);
                    q[rr] += __shfl_xor(q[rr], m);
                }
            }
            float mean[4], inv[4];
            #pragma unroll
            for (int rr = 0; rr < 4; ++rr){
                mean[rr] = s[rr] * (1.0f / 128.0f);
                float var = q[rr] * (1.0f / 128.0f) - mean[rr] * mean[rr];
                inv[rr] = rsqrtf(var + LN_EPS);
            }
            #pragma unroll
            for (int nt = 0; nt < 4; ++nt)
                #pragma unroll
                for (int rr = 0; rr < 4; ++rr){
                    float zf = (z[nt][rr]     - mean[rr]) * inv[rr] * gv[nt]     + bev[nt];
                    float zc = (z[nt + 4][rr] - mean[rr]) * inv[rr] * gv[nt + 4] + bev[nt + 4];
                    float p = sigmoidf_(zf) * softplusf_(zc);
                    prod[w * 16 + lg * 4 + rr][nt * 16 + lr] = p;
                }
        }
        __syncthreads();

        // epilogue: per-atom reduction over 12 rows + residual + softplus
        if (t < 64){
            int al_ = t >> 4;              // 0..3
            int c0 = (t & 15) * 4;         // 4 consecutive channels
            float4 sm = make_float4(0, 0, 0, 0);
            #pragma unroll
            for (int m = 0; m < 12; ++m){
                const float4 pv = *(const float4*)&prod[al_ * 12 + m][c0];
                sm.x += pv.x; sm.y += pv.y; sm.z += pv.z; sm.w += pv.w;
            }
            int atom = blk * BA + al_;
            float4 sf;
            if (layer == 0) sf = *(const float4*)(atom0F + (long)atom * 64 + c0);
            else            sf = *(const float4*)(&sSF[al_][c0]);
            float o[4];
            o[0] = softplusf_(sf.x + sm.x);
            o[1] = softplusf_(sf.y + sm.y);
            o[2] = softplusf_(sf.z + sm.z);
            o[3] = softplusf_(sf.w + sm.w);
            if (layer == 0){
                *(float4*)(&sSF[al_][c0]) = make_float4(o[0], o[1], o[2], o[3]);
                u16 h0,l0_,h1,l1_,h2,l2_,h3,l3_;
                split_bf16(o[0], h0, l0_); split_bf16(o[1], h1, l1_);
                split_bf16(o[2], h2, l2_); split_bf16(o[3], h3, l3_);
                ushort4 hv; hv.x=h0; hv.y=h1; hv.z=h2; hv.w=h3;
                ushort4 lv; lv.x=l0_; lv.y=l1_; lv.z=l2_; lv.w=l3_;
                *(ushort4*)(&sSH[al_][c0]) = hv;
                *(ushort4*)(&sSL[al_][c0]) = lv;
            } else {
                *(float4*)(outF + (long)atom * 64 + c0) = make_float4(o[0], o[1], o[2], o[3]);
            }
        }
        __syncthreads();
    }
}

// ---------------- pooling: deterministic two-stage tree ----------------
__global__ __launch_bounds__(256) void k_partial(const float* __restrict__ atom,
        const float* __restrict__ occ, float* __restrict__ partials){
    int b = blockIdx.x, tid = threadIdx.x;
    int f = tid & 63, sub = tid >> 6;
    __shared__ float sAcc[256];
    float acc = 0.0f;
    for (int it = 0; it < 16; ++it){
        int a = b * 64 + sub + it * 4;
        float p = sigmoidf_(occ[a]);
        acc += atom[(long)a * FEA + f] * p;
    }
    sAcc[tid] = acc;
    __syncthreads();
    if (tid < 64){
        float s = sAcc[f] + sAcc[64 + f] + sAcc[128 + f] + sAcc[192 + f];
        partials[b * 65 + f] = s;
        float po = sigmoidf_(occ[b * 64 + f]);
        #pragma unroll
        for (int off = 32; off; off >>= 1) po += __shfl_down(po, off);
        if (f == 0) partials[b * 65 + 64] = po;
    }
}

__global__ __launch_bounds__(64) void k_final(const float* __restrict__ partials,
        const float* __restrict__ fc_w, const float* __restrict__ fc_b,
        float* __restrict__ out){
    int f = threadIdx.x;
    float num = 0.0f;
    for (int p = 0; p < 64; ++p) num += partials[p * 65 + f];
    float occs = partials[f * 65 + 64];
    #pragma unroll
    for (int off = 32; off; off >>= 1) occs += __shfl_down(occs, off);
    occs = __shfl(occs, 0);
    float gf = num / (occs + 1e-6f);
    float v = gf * fc_w[f];
    #pragma unroll
    for (int off = 32; off; off >>= 1) v += __shfl_down(v, off);
    if (f == 0) out[0] = v + fc_b[0];
}

extern "C" void kernel_launch(void* const* d_in, const int* in_sizes, int n_in,
                              void* d_out, int out_size, void* d_ws, size_t ws_size,
                              hipStream_t stream) {
    const float* lat    = (const float*)d_in[0];
    const float* fracs  = (const float*)d_in[1];
    const float* slog   = (const float*)d_in[2];
    const float* occ    = (const float*)d_in[3];
    const float* emb_w  = (const float*)d_in[4];
    const float* emb_b  = (const float*)d_in[5];
    const float* w1     = (const float*)d_in[6];
    const float* b1     = (const float*)d_in[7];
    const float* g1     = (const float*)d_in[8];
    const float* be1    = (const float*)d_in[9];
    const float* w2     = (const float*)d_in[10];
    const float* b2     = (const float*)d_in[11];
    const float* g2     = (const float*)d_in[12];
    const float* be2    = (const float*)d_in[13];
    const float* fc_w   = (const float*)d_in[14];
    const float* fc_b   = (const float*)d_in[15];
    float* out = (float*)d_out;

    char* ws = (char*)d_ws;
    auto alloc = [&](size_t bytes) -> void* {
        void* p = (void*)ws;
        ws += (bytes + 255) & ~(size_t)255;
        return p;
    };
    int*   nbr_idx  = (int*)  alloc((size_t)N_ATOMS * M_NBR * 4);
    float* nbr_dist = (float*)alloc((size_t)N_ATOMS * M_NBR * 4);
    float* atom0    = (float*)alloc((size_t)N_ATOMS * FEA * 4);
    float* atom1    = (float*)alloc((size_t)N_ATOMS * FEA * 4);
    u16*   a0h      = (u16*)  alloc((size_t)N_ATOMS * FEA * 2);
    u16*   a0l      = (u16*)  alloc((size_t)N_ATOMS * FEA * 2);
    u16*   wt1h     = (u16*)  alloc((size_t)192 * 128 * 2);
    u16*   wt1l     = (u16*)  alloc((size_t)192 * 128 * 2);
    u16*   wt2h     = (u16*)  alloc((size_t)192 * 128 * 2);
    u16*   wt2l     = (u16*)  alloc((size_t)192 * 128 * 2);
    float* fxa      = (float*)alloc((size_t)N_ATOMS * 4);
    float* fya      = (float*)alloc((size_t)N_ATOMS * 4);
    float* fza      = (float*)alloc((size_t)N_ATOMS * 4);
    float* partials = (float*)alloc((size_t)64 * 65 * 4);

    k_prep   <<<N_ATOMS / 256, 256, 0, stream>>>(fracs, fxa, fya, fza);
    k_prepw  <<<192, 256, 0, stream>>>(w1, w2, wt1h, wt1l, wt2h, wt2l);
    k_embed  <<<N_ATOMS / 4, 256, 0, stream>>>(slog, emb_w, emb_b, atom0, a0h, a0l);
    k_topk   <<<N_ATOMS, 256, 0, stream>>>(fxa, fya, fza, lat, nbr_idx, nbr_dist);
    k_layer2 <<<N_ATOMS / BA, 192, 0, stream>>>(atom0, a0h, a0l, nbr_idx, nbr_dist,
                wt1h, wt1l, b1, g1, be1, wt2h, wt2l, b2, g2, be2, atom1);
    k_partial<<<64, 256, 0, stream>>>(atom1, occ, partials);
    k_final  <<<1, 64, 0, stream>>>(partials, fc_w, fc_b, out);
}

// Round 5
// 122.103 us; speedup vs baseline: 1.4707x; 1.0026x over previous
//
#include <hip/hip_runtime.h>
#include <math.h>

#define N_ATOMS 4096
#define SPECIES 100
#define FEA 64
#define M_NBR 12

typedef unsigned short u16;
typedef __attribute__((ext_vector_type(8))) _Float16 f16x8;
typedef __attribute__((ext_vector_type(4))) float f32x4;

constexpr float LN_EPS = 1e-5f;
constexpr float GAUSS_COEFF = -31.0078125f; // -0.5/(8/63)^2
constexpr float D2_INF = 3.4e38f;

__device__ __forceinline__ float sigmoidf_(float x){ return 1.0f/(1.0f+__expf(-x)); }
__device__ __forceinline__ float softplusf_(float x){
    return fmaxf(x, 0.0f) + log1pf(__expf(-fabsf(x)));
}
__device__ __forceinline__ u16 f16bits(_Float16 h){ return *(u16*)&h; }
// split f32 into fp16 hi + fp16 lo
__device__ __forceinline__ void split_f16(float x, u16& h, u16& l){
    _Float16 hh = (_Float16)x;
    float hf = (float)hh;
    _Float16 ll = (_Float16)(x - hf);
    h = f16bits(hh); l = f16bits(ll);
}

// ---------------- fracs transpose: [N,3] -> fx,fy,fz ----------------
__global__ __launch_bounds__(256) void k_prep(const float* __restrict__ fracs,
        float* __restrict__ fx, float* __restrict__ fy, float* __restrict__ fz){
    int j = blockIdx.x * 256 + threadIdx.x;
    fx[j] = fracs[j*3+0];
    fy[j] = fracs[j*3+1];
    fz[j] = fracs[j*3+2];
}

// ---------------- weight prep: W[192][128] f32 -> fp16, per-(ch,nt) wave-contiguous ----------
// dest[((ch*8+nt)*64 + lane)*8 + i] = (fp16) W[k=ch*32+lg*8+i][n=nt*16+lr], lane=lg*16+lr
__global__ __launch_bounds__(256) void k_prepw(const float* __restrict__ w1,
        const float* __restrict__ w2, u16* __restrict__ w1f, u16* __restrict__ w2f){
    int gid = blockIdx.x * 256 + threadIdx.x;      // 0..49151
    int layer = gid / 24576;
    int e = gid % 24576;
    int k = e >> 7, n = e & 127;
    const float* w = layer ? w2 : w1;
    float x = w[e];
    int ch = k >> 5, lg = (k >> 3) & 3, i = k & 7;
    int nt = n >> 4, lr = n & 15;
    int lane = lg * 16 + lr;
    int dest = ((ch * 8 + nt) * 64 + lane) * 8 + i;
    u16* tf = layer ? w2f : w1f;
    tf[dest] = f16bits((_Float16)x);
}

// ---------------- embedding: softmax(species_logits) @ emb_w + emb_b ----------------
__global__ __launch_bounds__(256) void k_embed(const float* __restrict__ logits,
        const float* __restrict__ emb_w, const float* __restrict__ emb_b,
        float* __restrict__ atom0, u16* __restrict__ a0h, u16* __restrict__ a0l){
    __shared__ float sE[4][SPECIES];
    int tid = threadIdx.x;
    int grp = tid >> 6;
    int f = tid & 63;
    int a = blockIdx.x * 4 + grp;
    const float* lg = logits + (long)a * SPECIES;
    float l0 = lg[f];
    float l1 = (f + 64 < SPECIES) ? lg[f + 64] : -1e30f;
    float mx = fmaxf(l0, l1);
    #pragma unroll
    for (int off = 32; off; off >>= 1) mx = fmaxf(mx, __shfl_xor(mx, off));
    float e0 = __expf(l0 - mx);
    float e1 = (f + 64 < SPECIES) ? __expf(l1 - mx) : 0.0f;
    sE[grp][f] = e0;
    if (f + 64 < SPECIES) sE[grp][64 + f] = e1;
    float sm = e0 + e1;
    #pragma unroll
    for (int off = 32; off; off >>= 1) sm += __shfl_xor(sm, off);
    __syncthreads();
    float acc = 0.0f;
    for (int s = 0; s < SPECIES; ++s) acc += sE[grp][s] * emb_w[s * FEA + f];
    float v = acc / sm + emb_b[f];
    atom0[(long)a * FEA + f] = v;
    u16 h, lo; split_f16(v, h, lo);
    a0h[a * FEA + f] = h;
    a0l[a * FEA + f] = lo;
}

// ---------------- top-12 via histogram threshold + candidate compaction ----------------
__global__ __launch_bounds__(256) void k_topk(const float* __restrict__ fx,
        const float* __restrict__ fy, const float* __restrict__ fz,
        const float* __restrict__ lat, int* __restrict__ nbr_idx,
        float* __restrict__ nbr_dist){
    __shared__ int   hist[256];
    __shared__ int   cnt;
    __shared__ float sThr;
    __shared__ float candD[256];
    __shared__ int   candI[256];
    int i = blockIdx.x, tid = threadIdx.x;
    hist[tid] = 0;
    if (tid == 0) cnt = 0;
    __syncthreads();
    float l00=lat[0],l01=lat[1],l02=lat[2];
    float l10=lat[3],l11=lat[4],l12=lat[5];
    float l20=lat[6],l21=lat[7],l22=lat[8];
    float xi = fx[i], yi = fy[i], zi = fz[i];
    float d2r[16];
    #pragma unroll
    for (int k = 0; k < 16; ++k){
        int j = tid + k * 256;
        float dx = xi - fx[j];
        float dy = yi - fy[j];
        float dz = zi - fz[j];
        dx -= rintf(dx); dy -= rintf(dy); dz -= rintf(dz);
        float cx = dx*l00 + dy*l10 + dz*l20;
        float cy = dx*l01 + dy*l11 + dz*l21;
        float cz = dx*l02 + dy*l12 + dz*l22;
        float d2 = cx*cx + cy*cy + cz*cz;
        if (j == i) d2 = D2_INF;
        d2r[k] = d2;
        if (d2 < 4.0f) atomicAdd(&hist[(int)(d2 * 64.0f)], 1);
    }
    __syncthreads();
    if (tid < 64){
        int s0 = hist[4*tid] + hist[4*tid+1] + hist[4*tid+2] + hist[4*tid+3];
        int sc = s0;
        #pragma unroll
        for (int off = 1; off < 64; off <<= 1){
            int o = __shfl_up(sc, off);
            if (tid >= off) sc += o;
        }
        unsigned long long mball = __ballot(sc >= M_NBR);
        if (mball == 0ULL){
            if (tid == 0) sThr = 1e30f;
        } else {
            int gbin = __ffsll(mball) - 1;
            if (tid == gbin){
                int c = sc - s0;
                float th = 4.0f;
                #pragma unroll
                for (int b = 0; b < 4; ++b){
                    c += hist[4*gbin + b];
                    if (c >= M_NBR){ th = (float)(4*gbin + b + 1) * (1.0f/64.0f); break; }
                }
                sThr = th;
            }
        }
    }
    __syncthreads();
    float thr = sThr;
    #pragma unroll
    for (int k = 0; k < 16; ++k){
        if (d2r[k] < thr){
            int p = atomicAdd(&cnt, 1);
            if (p < 256){ candD[p] = d2r[k]; candI[p] = tid + k * 256; }
        }
    }
    __syncthreads();
    if (tid < 64){
        int n = cnt < 256 ? cnt : 256;
        float v0 = (tid       < n) ? candD[tid]       : D2_INF;
        int   i0 = (tid       < n) ? candI[tid]       : 0x7FFFFFFF;
        float v1 = (tid + 64  < n) ? candD[tid + 64]  : D2_INF;
        int   i1 = (tid + 64  < n) ? candI[tid + 64]  : 0x7FFFFFFF;
        float v2 = (tid + 128 < n) ? candD[tid + 128] : D2_INF;
        int   i2 = (tid + 128 < n) ? candI[tid + 128] : 0x7FFFFFFF;
        float v3 = (tid + 192 < n) ? candD[tid + 192] : D2_INF;
        int   i3 = (tid + 192 < n) ? candI[tid + 192] : 0x7FFFFFFF;
        for (int r = 0; r < M_NBR; ++r){
            float bv = v0; int bi = i0;
            if (v1 < bv || (v1 == bv && i1 < bi)){ bv = v1; bi = i1; }
            if (v2 < bv || (v2 == bv && i2 < bi)){ bv = v2; bi = i2; }
            if (v3 < bv || (v3 == bv && i3 < bi)){ bv = v3; bi = i3; }
            #pragma unroll
            for (int off = 1; off < 64; off <<= 1){
                float ov = __shfl_xor(bv, off);
                int   oi = __shfl_xor(bi, off);
                if (ov < bv || (ov == bv && oi < bi)){ bv = ov; bi = oi; }
            }
            if (i0 == bi) v0 = D2_INF;
            if (i1 == bi) v1 = D2_INF;
            if (i2 == bi) v2 = D2_INF;
            if (i3 == bi) v3 = D2_INF;
            if (tid == 0){
                nbr_idx[i * M_NBR + r]  = bi;
                nbr_dist[i * M_NBR + r] = sqrtf(bv);
            }
        }
    }
}

// ---------------- fused CGCNN layers 1+2, fp16 MFMA, W staged in LDS ----------------
// 8 atoms/block (96 rows = 6 M-tiles), 3 waves x 2 M-tiles x 8 N-tiles, grid 512 (2 blk/CU).
// A = (self | nbr | gauss) rows; B = W^T fp16 in LDS (48KB/layer, restaged per layer).
// A split fp16 hi/lo for feature chunks, single fp16 for gaussians; accumulate f32.
__global__ __launch_bounds__(192) void k_layer2(
        const float* __restrict__ atom0F,
        const u16* __restrict__ a0h, const u16* __restrict__ a0l,
        const int* __restrict__ nbr_idx, const float* __restrict__ nbr_dist,
        const u16* __restrict__ w1f, const float* __restrict__ b1,
        const float* __restrict__ g1, const float* __restrict__ be1,
        const u16* __restrict__ w2f, const float* __restrict__ b2,
        const float* __restrict__ g2, const float* __restrict__ be2,
        float* __restrict__ outF)
{
    __shared__ u16   wlds[24576];      // 48KB: staged W (fp16), per-(ch,nt) contiguous
    __shared__ float prod[96][68];     // 26.1KB
    __shared__ float sSF[8][64];       // 2KB   layer-1 output f32
    __shared__ u16   sSH[8][64];       // 1KB   layer-1 output fp16 hi
    __shared__ u16   sSL[8][64];       // 1KB   layer-1 output fp16 lo

    const int t = threadIdx.x;
    const int w = t / 64, l = t & 63;
    const int lg = l >> 4, lr = l & 15;
    const int blk = blockIdx.x;

    // --- stage W1 (issue first so loads are in flight during prologue) ---
    #pragma unroll
    for (int it = 0; it < 16; ++it){
        int off8 = (it * 192 + t) * 8;
        *(float4*)(&wlds[off8]) = *(const float4*)(w1f + off8);
    }

    int aidx[2], nidx[2], aloc[2];
    float dist[2];
    #pragma unroll
    for (int mt = 0; mt < 2; ++mt){
        int rloc = w * 32 + mt * 16 + lr;
        int r = blk * 96 + rloc;
        aidx[mt] = r / 12;
        aloc[mt] = rloc / 12;
        nidx[mt] = nbr_idx[r];
        dist[mt] = nbr_dist[r];
    }

    // gaussian fragments (chunks 4,5): single fp16, shared by both layers
    f16x8 gh[2][2];
    #pragma unroll
    for (int mt = 0; mt < 2; ++mt)
        #pragma unroll
        for (int c = 0; c < 2; ++c)
            #pragma unroll
            for (int i = 0; i < 8; ++i){
                int k = c * 32 + lg * 8 + i;
                float off = (float)k * (8.0f / 63.0f);
                float dd = dist[mt] - off;
                gh[mt][c][i] = (_Float16)__expf(GAUSS_COEFF * dd * dd);
            }
    // neighbor fragments (chunks 2,3): fp16 hi/lo, shared by both layers
    f16x8 nh[2][2], nl[2][2];
    #pragma unroll
    for (int mt = 0; mt < 2; ++mt)
        #pragma unroll
        for (int c = 0; c < 2; ++c){
            int o = nidx[mt] * 64 + c * 32 + lg * 8;
            nh[mt][c] = *(const f16x8*)(a0h + o);
            nl[mt][c] = *(const f16x8*)(a0l + o);
        }
    __syncthreads();   // W1 staged

    #pragma unroll
    for (int layer = 0; layer < 2; ++layer){
        const float* bias = layer ? b2 : b1;
        const float* gga  = layer ? g2 : g1;
        const float* bba  = layer ? be2 : be1;

        // self fragments (chunks 0,1)
        f16x8 sh[2][2], sl[2][2];
        #pragma unroll
        for (int mt = 0; mt < 2; ++mt)
            #pragma unroll
            for (int c = 0; c < 2; ++c){
                if (layer == 0){
                    int o = aidx[mt] * 64 + c * 32 + lg * 8;
                    sh[mt][c] = *(const f16x8*)(a0h + o);
                    sl[mt][c] = *(const f16x8*)(a0l + o);
                } else {
                    sh[mt][c] = *(const f16x8*)(&sSH[aloc[mt]][c * 32 + lg * 8]);
                    sl[mt][c] = *(const f16x8*)(&sSL[aloc[mt]][c * 32 + lg * 8]);
                }
            }

        float bv[8], gv[8], bev[8];
        #pragma unroll
        for (int nt = 0; nt < 8; ++nt){
            int c = nt * 16 + lr;
            bv[nt] = bias[c]; gv[nt] = gga[c]; bev[nt] = bba[c];
        }

        f32x4 acc[2][8];
        #pragma unroll
        for (int mt = 0; mt < 2; ++mt)
            #pragma unroll
            for (int nt = 0; nt < 8; ++nt) acc[mt][nt] = 0.0f;

        #pragma unroll
        for (int ch = 0; ch < 6; ++ch){
            #pragma unroll
            for (int nt = 0; nt < 8; ++nt){
                const f16x8 b = *(const f16x8*)(&wlds[((ch * 8 + nt) * 64 + l) * 8]);
                #pragma unroll
                for (int mt = 0; mt < 2; ++mt){
                    if (ch < 4){
                        f16x8 alo = (ch < 2) ? sl[mt][ch] : nl[mt][ch - 2];
                        acc[mt][nt] = __builtin_amdgcn_mfma_f32_16x16x32_f16(alo, b, acc[mt][nt], 0, 0, 0);
                    }
                    f16x8 ahi = (ch < 2) ? sh[mt][ch] : (ch < 4) ? nh[mt][ch - 2] : gh[mt][ch - 4];
                    acc[mt][nt] = __builtin_amdgcn_mfma_f32_16x16x32_f16(ahi, b, acc[mt][nt], 0, 0, 0);
                }
            }
        }

        // LayerNorm per row over 128 cols (in registers; row = lg*4+rr in one 16-lane group)
        #pragma unroll
        for (int mt = 0; mt < 2; ++mt){
            float s[4] = {0,0,0,0}, q[4] = {0,0,0,0};
            #pragma unroll
            for (int nt = 0; nt < 8; ++nt)
                #pragma unroll
                for (int rr = 0; rr < 4; ++rr){
                    float v = acc[mt][nt][rr] + bv[nt];
                    acc[mt][nt][rr] = v;
                    s[rr] += v; q[rr] += v * v;
                }
            #pragma unroll
            for (int rr = 0; rr < 4; ++rr){
                #pragma unroll
                for (int m = 1; m < 16; m <<= 1){
                    s[rr] += __shfl_xor(s[rr], m);
                    q[rr] += __shfl_xor(q[rr], m);
                }
            }
            #pragma unroll
            for (int rr = 0; rr < 4; ++rr){
                float mean = s[rr] * (1.0f / 128.0f);
                float var  = q[rr] * (1.0f / 128.0f) - mean * mean;
                float inv  = rsqrtf(var + LN_EPS);
                #pragma unroll
                for (int nt = 0; nt < 4; ++nt){
                    float zf = (acc[mt][nt][rr]     - mean) * inv * gv[nt]     + bev[nt];
                    float zc = (acc[mt][nt + 4][rr] - mean) * inv * gv[nt + 4] + bev[nt + 4];
                    prod[w * 32 + mt * 16 + lg * 4 + rr][nt * 16 + lr] = sigmoidf_(zf) * softplusf_(zc);
                }
            }
        }
        __syncthreads();   // prod complete; all wlds reads done

        if (layer == 0){
            // stage W2 (overlaps epilogue)
            #pragma unroll
            for (int it = 0; it < 16; ++it){
                int off8 = (it * 192 + t) * 8;
                *(float4*)(&wlds[off8]) = *(const float4*)(w2f + off8);
            }
        }

        // epilogue: per-atom reduction over 12 rows + residual + softplus
        if (t < 128){
            int a_ = t >> 4;               // 0..7
            int c0 = (t & 15) * 4;
            float4 sm = make_float4(0, 0, 0, 0);
            #pragma unroll
            for (int m = 0; m < 12; ++m){
                const float4 pv = *(const float4*)&prod[a_ * 12 + m][c0];
                sm.x += pv.x; sm.y += pv.y; sm.z += pv.z; sm.w += pv.w;
            }
            int atom = blk * 8 + a_;
            float4 sf;
            if (layer == 0) sf = *(const float4*)(atom0F + (long)atom * 64 + c0);
            else            sf = *(const float4*)(&sSF[a_][c0]);
            float o0 = softplusf_(sf.x + sm.x);
            float o1 = softplusf_(sf.y + sm.y);
            float o2 = softplusf_(sf.z + sm.z);
            float o3 = softplusf_(sf.w + sm.w);
            if (layer == 0){
                *(float4*)(&sSF[a_][c0]) = make_float4(o0, o1, o2, o3);
                u16 h0,l0_,h1,l1_,h2,l2_,h3,l3_;
                split_f16(o0, h0, l0_); split_f16(o1, h1, l1_);
                split_f16(o2, h2, l2_); split_f16(o3, h3, l3_);
                ushort4 hv; hv.x=h0; hv.y=h1; hv.z=h2; hv.w=h3;
                ushort4 lv; lv.x=l0_; lv.y=l1_; lv.z=l2_; lv.w=l3_;
                *(ushort4*)(&sSH[a_][c0]) = hv;
                *(ushort4*)(&sSL[a_][c0]) = lv;
            } else {
                *(float4*)(outF + (long)atom * 64 + c0) = make_float4(o0, o1, o2, o3);
            }
        }
        __syncthreads();   // stash + W2 ready before layer 2 reads
    }
}

// ---------------- pooling: deterministic two-stage tree ----------------
__global__ __launch_bounds__(256) void k_partial(const float* __restrict__ atom,
        const float* __restrict__ occ, float* __restrict__ partials){
    int b = blockIdx.x, tid = threadIdx.x;
    int f = tid & 63, sub = tid >> 6;
    __shared__ float sAcc[256];
    float acc = 0.0f;
    for (int it = 0; it < 16; ++it){
        int a = b * 64 + sub + it * 4;
        float p = sigmoidf_(occ[a]);
        acc += atom[(long)a * FEA + f] * p;
    }
    sAcc[tid] = acc;
    __syncthreads();
    if (tid < 64){
        float s = sAcc[f] + sAcc[64 + f] + sAcc[128 + f] + sAcc[192 + f];
        partials[b * 65 + f] = s;
        float po = sigmoidf_(occ[b * 64 + f]);
        #pragma unroll
        for (int off = 32; off; off >>= 1) po += __shfl_down(po, off);
        if (f == 0) partials[b * 65 + 64] = po;
    }
}

__global__ __launch_bounds__(64) void k_final(const float* __restrict__ partials,
        const float* __restrict__ fc_w, const float* __restrict__ fc_b,
        float* __restrict__ out){
    int f = threadIdx.x;
    float num = 0.0f;
    for (int p = 0; p < 64; ++p) num += partials[p * 65 + f];
    float occs = partials[f * 65 + 64];
    #pragma unroll
    for (int off = 32; off; off >>= 1) occs += __shfl_down(occs, off);
    occs = __shfl(occs, 0);
    float gf = num / (occs + 1e-6f);
    float v = gf * fc_w[f];
    #pragma unroll
    for (int off = 32; off; off >>= 1) v += __shfl_down(v, off);
    if (f == 0) out[0] = v + fc_b[0];
}

extern "C" void kernel_launch(void* const* d_in, const int* in_sizes, int n_in,
                              void* d_out, int out_size, void* d_ws, size_t ws_size,
                              hipStream_t stream) {
    const float* lat    = (const float*)d_in[0];
    const float* fracs  = (const float*)d_in[1];
    const float* slog   = (const float*)d_in[2];
    const float* occ    = (const float*)d_in[3];
    const float* emb_w  = (const float*)d_in[4];
    const float* emb_b  = (const float*)d_in[5];
    const float* w1     = (const float*)d_in[6];
    const float* b1     = (const float*)d_in[7];
    const float* g1     = (const float*)d_in[8];
    const float* be1    = (const float*)d_in[9];
    const float* w2     = (const float*)d_in[10];
    const float* b2     = (const float*)d_in[11];
    const float* g2     = (const float*)d_in[12];
    const float* be2    = (const float*)d_in[13];
    const float* fc_w   = (const float*)d_in[14];
    const float* fc_b   = (const float*)d_in[15];
    float* out = (float*)d_out;

    char* ws = (char*)d_ws;
    auto alloc = [&](size_t bytes) -> void* {
        void* p = (void*)ws;
        ws += (bytes + 255) & ~(size_t)255;
        return p;
    };
    int*   nbr_idx  = (int*)  alloc((size_t)N_ATOMS * M_NBR * 4);
    float* nbr_dist = (float*)alloc((size_t)N_ATOMS * M_NBR * 4);
    float* atom0    = (float*)alloc((size_t)N_ATOMS * FEA * 4);
    float* atom1    = (float*)alloc((size_t)N_ATOMS * FEA * 4);
    u16*   a0h      = (u16*)  alloc((size_t)N_ATOMS * FEA * 2);
    u16*   a0l      = (u16*)  alloc((size_t)N_ATOMS * FEA * 2);
    u16*   w1f      = (u16*)  alloc((size_t)192 * 128 * 2);
    u16*   w2f      = (u16*)  alloc((size_t)192 * 128 * 2);
    float* fxa      = (float*)alloc((size_t)N_ATOMS * 4);
    float* fya      = (float*)alloc((size_t)N_ATOMS * 4);
    float* fza      = (float*)alloc((size_t)N_ATOMS * 4);
    float* partials = (float*)alloc((size_t)64 * 65 * 4);

    k_prep   <<<N_ATOMS / 256, 256, 0, stream>>>(fracs, fxa, fya, fza);
    k_prepw  <<<192, 256, 0, stream>>>(w1, w2, w1f, w2f);
    k_embed  <<<N_ATOMS / 4, 256, 0, stream>>>(slog, emb_w, emb_b, atom0, a0h, a0l);
    k_topk   <<<N_ATOMS, 256, 0, stream>>>(fxa, fya, fza, lat, nbr_idx, nbr_dist);
    k_layer2 <<<N_ATOMS / 8, 192, 0, stream>>>(atom0, a0h, a0l, nbr_idx, nbr_dist,
                w1f, b1, g1, be1, w2f, b2, g2, be2, atom1);
    k_partial<<<64, 256, 0, stream>>>(atom1, occ, partials);
    k_final  <<<1, 64, 0, stream>>>(partials, fc_w, fc_b, out);
}

// Round 6
// 115.633 us; speedup vs baseline: 1.5530x; 1.0559x over previous
//
#include <hip/hip_runtime.h>
#include <math.h>

#define N_ATOMS 4096
#define SPECIES 100
#define FEA 64
#define M_NBR 12

typedef unsigned short u16;
typedef __attribute__((ext_vector_type(8))) _Float16 f16x8;
typedef __attribute__((ext_vector_type(4))) float f32x4;

constexpr float LN_EPS = 1e-5f;
constexpr float GAUSS_COEFF = -31.0078125f; // -0.5/(8/63)^2
constexpr float D2_INF = 3.4e38f;

__device__ __forceinline__ float sigmoidf_(float x){ return 1.0f/(1.0f+__expf(-x)); }
__device__ __forceinline__ float softplusf_(float x){
    return fmaxf(x, 0.0f) + log1pf(__expf(-fabsf(x)));
}
__device__ __forceinline__ u16 f16bits(_Float16 h){ return *(u16*)&h; }

// ---------------- setup: fracs transpose + weight fp16 transpose-pack ----------------
// W layout: dest[((ch*8+nt)*64 + lane)*8 + i] = (fp16) W[k=ch*32+lg*8+i][n=nt*16+lr],
// lane = lg*16+lr  ->  per-(ch,nt) the wave's 64 lanes read one contiguous 1KB chunk.
__global__ __launch_bounds__(256) void k_setup(const float* __restrict__ fracs,
        const float* __restrict__ w1, const float* __restrict__ w2,
        float* __restrict__ fx, float* __restrict__ fy, float* __restrict__ fz,
        u16* __restrict__ w1f, u16* __restrict__ w2f){
    int b = blockIdx.x, t = threadIdx.x;
    if (b < 192){
        int gid = b * 256 + t;             // 0..49151
        int layer = gid / 24576;
        int e = gid % 24576;
        int k = e >> 7, n = e & 127;
        const float* w = layer ? w2 : w1;
        float x = w[e];
        int ch = k >> 5, lg = (k >> 3) & 3, i = k & 7;
        int nt = n >> 4, lr = n & 15;
        int lane = lg * 16 + lr;
        int dest = ((ch * 8 + nt) * 64 + lane) * 8 + i;
        (layer ? w2f : w1f)[dest] = f16bits((_Float16)x);
    } else {
        int j = (b - 192) * 256 + t;
        fx[j] = fracs[j*3+0];
        fy[j] = fracs[j*3+1];
        fz[j] = fracs[j*3+2];
    }
}

// ---------------- embedding: softmax(species_logits) @ emb_w + emb_b ----------------
__global__ __launch_bounds__(256) void k_embed(const float* __restrict__ logits,
        const float* __restrict__ emb_w, const float* __restrict__ emb_b,
        float* __restrict__ atom0, u16* __restrict__ a0f){
    __shared__ float sE[4][SPECIES];
    int tid = threadIdx.x;
    int grp = tid >> 6;
    int f = tid & 63;
    int a = blockIdx.x * 4 + grp;
    const float* lg = logits + (long)a * SPECIES;
    float l0 = lg[f];
    float l1 = (f + 64 < SPECIES) ? lg[f + 64] : -1e30f;
    float mx = fmaxf(l0, l1);
    #pragma unroll
    for (int off = 32; off; off >>= 1) mx = fmaxf(mx, __shfl_xor(mx, off));
    float e0 = __expf(l0 - mx);
    float e1 = (f + 64 < SPECIES) ? __expf(l1 - mx) : 0.0f;
    sE[grp][f] = e0;
    if (f + 64 < SPECIES) sE[grp][64 + f] = e1;
    float sm = e0 + e1;
    #pragma unroll
    for (int off = 32; off; off >>= 1) sm += __shfl_xor(sm, off);
    __syncthreads();
    float acc = 0.0f;
    for (int s = 0; s < SPECIES; ++s) acc += sE[grp][s] * emb_w[s * FEA + f];
    float v = acc / sm + emb_b[f];
    atom0[(long)a * FEA + f] = v;
    a0f[a * FEA + f] = f16bits((_Float16)v);
}

// ---------------- top-12 via histogram threshold + candidate compaction ----------------
__global__ __launch_bounds__(256) void k_topk(const float* __restrict__ fx,
        const float* __restrict__ fy, const float* __restrict__ fz,
        const float* __restrict__ lat, int* __restrict__ nbr_idx,
        float* __restrict__ nbr_dist){
    __shared__ int   hist[256];
    __shared__ int   cnt;
    __shared__ float sThr;
    __shared__ float candD[256];
    __shared__ int   candI[256];
    int i = blockIdx.x, tid = threadIdx.x;
    hist[tid] = 0;
    if (tid == 0) cnt = 0;
    __syncthreads();
    float l00=lat[0],l01=lat[1],l02=lat[2];
    float l10=lat[3],l11=lat[4],l12=lat[5];
    float l20=lat[6],l21=lat[7],l22=lat[8];
    float xi = fx[i], yi = fy[i], zi = fz[i];
    float d2r[16];
    #pragma unroll
    for (int k = 0; k < 16; ++k){
        int j = tid + k * 256;
        float dx = xi - fx[j];
        float dy = yi - fy[j];
        float dz = zi - fz[j];
        dx -= rintf(dx); dy -= rintf(dy); dz -= rintf(dz);
        float cx = dx*l00 + dy*l10 + dz*l20;
        float cy = dx*l01 + dy*l11 + dz*l21;
        float cz = dx*l02 + dy*l12 + dz*l22;
        float d2 = cx*cx + cy*cy + cz*cz;
        if (j == i) d2 = D2_INF;
        d2r[k] = d2;
        if (d2 < 4.0f) atomicAdd(&hist[(int)(d2 * 64.0f)], 1);
    }
    __syncthreads();
    if (tid < 64){
        int s0 = hist[4*tid] + hist[4*tid+1] + hist[4*tid+2] + hist[4*tid+3];
        int sc = s0;
        #pragma unroll
        for (int off = 1; off < 64; off <<= 1){
            int o = __shfl_up(sc, off);
            if (tid >= off) sc += o;
        }
        unsigned long long mball = __ballot(sc >= M_NBR);
        if (mball == 0ULL){
            if (tid == 0) sThr = 1e30f;
        } else {
            int gbin = __ffsll(mball) - 1;
            if (tid == gbin){
                int c = sc - s0;
                float th = 4.0f;
                #pragma unroll
                for (int b = 0; b < 4; ++b){
                    c += hist[4*gbin + b];
                    if (c >= M_NBR){ th = (float)(4*gbin + b + 1) * (1.0f/64.0f); break; }
                }
                sThr = th;
            }
        }
    }
    __syncthreads();
    float thr = sThr;
    #pragma unroll
    for (int k = 0; k < 16; ++k){
        if (d2r[k] < thr){
            int p = atomicAdd(&cnt, 1);
            if (p < 256){ candD[p] = d2r[k]; candI[p] = tid + k * 256; }
        }
    }
    __syncthreads();
    if (tid < 64){
        int n = cnt < 256 ? cnt : 256;
        float v0 = (tid       < n) ? candD[tid]       : D2_INF;
        int   i0 = (tid       < n) ? candI[tid]       : 0x7FFFFFFF;
        float v1 = (tid + 64  < n) ? candD[tid + 64]  : D2_INF;
        int   i1 = (tid + 64  < n) ? candI[tid + 64]  : 0x7FFFFFFF;
        float v2 = (tid + 128 < n) ? candD[tid + 128] : D2_INF;
        int   i2 = (tid + 128 < n) ? candI[tid + 128] : 0x7FFFFFFF;
        float v3 = (tid + 192 < n) ? candD[tid + 192] : D2_INF;
        int   i3 = (tid + 192 < n) ? candI[tid + 192] : 0x7FFFFFFF;
        for (int r = 0; r < M_NBR; ++r){
            float bv = v0; int bi = i0;
            if (v1 < bv || (v1 == bv && i1 < bi)){ bv = v1; bi = i1; }
            if (v2 < bv || (v2 == bv && i2 < bi)){ bv = v2; bi = i2; }
            if (v3 < bv || (v3 == bv && i3 < bi)){ bv = v3; bi = i3; }
            #pragma unroll
            for (int off = 1; off < 64; off <<= 1){
                float ov = __shfl_xor(bv, off);
                int   oi = __shfl_xor(bi, off);
                if (ov < bv || (ov == bv && oi < bi)){ bv = ov; bi = oi; }
            }
            if (i0 == bi) v0 = D2_INF;
            if (i1 == bi) v1 = D2_INF;
            if (i2 == bi) v2 = D2_INF;
            if (i3 == bi) v3 = D2_INF;
            if (tid == 0){
                nbr_idx[i * M_NBR + r]  = bi;
                nbr_dist[i * M_NBR + r] = sqrtf(bv);
            }
        }
    }
}

// ---------------- fused CGCNN layers 1+2: one wave per block, 4 atoms (48 rows) ----------------
// 3 M-tiles x 8 N-tiles per wave; K=192 in 6 chunks of 32; fp16 MFMA, f32 accumulate.
// B read coalesced from global (L2-hot, 1KB per (ch,nt) per wave). Grid 1024 -> 8 waves/CU.
__global__ __launch_bounds__(64, 2) void k_fused(
        const float* __restrict__ atom0F, const u16* __restrict__ a0f,
        const int* __restrict__ nbr_idx, const float* __restrict__ nbr_dist,
        const u16* __restrict__ w1f, const float* __restrict__ b1,
        const float* __restrict__ g1, const float* __restrict__ be1,
        const u16* __restrict__ w2f, const float* __restrict__ b2,
        const float* __restrict__ g2, const float* __restrict__ be2,
        float* __restrict__ outF)
{
    __shared__ float prod[48][68];   // 13.1KB
    __shared__ float sSF[4][64];     // 1KB  layer-1 out f32 (residual for layer 2)
    __shared__ u16   sSH[4][64];     // 0.5KB layer-1 out fp16 (self frags for layer 2)
    const int l = threadIdx.x;
    const int lg = l >> 4, lr = l & 15;
    const int blk = blockIdx.x;

    int nidx[3], aidx[3];
    float dist[3];
    #pragma unroll
    for (int mt = 0; mt < 3; ++mt){
        int r = blk * 48 + mt * 16 + lr;
        aidx[mt] = r / 12;
        nidx[mt] = nbr_idx[r];
        dist[mt] = nbr_dist[r];
    }
    // gaussian fragments (chunks 4,5), shared by both layers
    f16x8 gfr[3][2];
    #pragma unroll
    for (int mt = 0; mt < 3; ++mt)
        #pragma unroll
        for (int c = 0; c < 2; ++c)
            #pragma unroll
            for (int i = 0; i < 8; ++i){
                int k = c * 32 + lg * 8 + i;
                float dd = dist[mt] - (float)k * (8.0f / 63.0f);
                gfr[mt][c][i] = (_Float16)__expf(GAUSS_COEFF * dd * dd);
            }
    // neighbor fragments (chunks 2,3), shared by both layers
    f16x8 nfr[3][2];
    #pragma unroll
    for (int mt = 0; mt < 3; ++mt)
        #pragma unroll
        for (int c = 0; c < 2; ++c)
            nfr[mt][c] = *(const f16x8*)(a0f + nidx[mt] * 64 + c * 32 + lg * 8);
    // self fragments (chunks 0,1) for layer 1
    f16x8 sfr[3][2];
    #pragma unroll
    for (int mt = 0; mt < 3; ++mt)
        #pragma unroll
        for (int c = 0; c < 2; ++c)
            sfr[mt][c] = *(const f16x8*)(a0f + aidx[mt] * 64 + c * 32 + lg * 8);

    #pragma unroll
    for (int layer = 0; layer < 2; ++layer){
        const u16* wf     = layer ? w2f : w1f;
        const float* bias = layer ? b2  : b1;
        const float* gga  = layer ? g2  : g1;
        const float* bba  = layer ? be2 : be1;

        float bv[8], gv[8], bev[8];
        #pragma unroll
        for (int nt = 0; nt < 8; ++nt){
            int c = nt * 16 + lr;
            bv[nt] = bias[c]; gv[nt] = gga[c]; bev[nt] = bba[c];
        }

        f32x4 acc[3][8];
        #pragma unroll
        for (int mt = 0; mt < 3; ++mt)
            #pragma unroll
            for (int nt = 0; nt < 8; ++nt) acc[mt][nt] = 0.0f;

        #pragma unroll
        for (int ch = 0; ch < 6; ++ch){
            #pragma unroll
            for (int nt = 0; nt < 8; ++nt){
                const f16x8 b = *(const f16x8*)(wf + ((ch * 8 + nt) * 64 + l) * 8);
                #pragma unroll
                for (int mt = 0; mt < 3; ++mt){
                    f16x8 a = (ch < 2) ? sfr[mt][ch] : (ch < 4) ? nfr[mt][ch - 2] : gfr[mt][ch - 4];
                    acc[mt][nt] = __builtin_amdgcn_mfma_f32_16x16x32_f16(a, b, acc[mt][nt], 0, 0, 0);
                }
            }
        }

        // LayerNorm per row over 128 cols (row = lg*4+rr lives in one 16-lane group)
        #pragma unroll
        for (int mt = 0; mt < 3; ++mt){
            float s[4] = {0,0,0,0}, q[4] = {0,0,0,0};
            #pragma unroll
            for (int nt = 0; nt < 8; ++nt)
                #pragma unroll
                for (int rr = 0; rr < 4; ++rr){
                    float v = acc[mt][nt][rr] + bv[nt];
                    acc[mt][nt][rr] = v;
                    s[rr] += v; q[rr] += v * v;
                }
            #pragma unroll
            for (int rr = 0; rr < 4; ++rr){
                #pragma unroll
                for (int m = 1; m < 16; m <<= 1){
                    s[rr] += __shfl_xor(s[rr], m);
                    q[rr] += __shfl_xor(q[rr], m);
                }
            }
            #pragma unroll
            for (int rr = 0; rr < 4; ++rr){
                float mean = s[rr] * (1.0f / 128.0f);
                float var  = q[rr] * (1.0f / 128.0f) - mean * mean;
                float inv  = rsqrtf(var + LN_EPS);
                #pragma unroll
                for (int nt = 0; nt < 4; ++nt){
                    float zf = (acc[mt][nt][rr]     - mean) * inv * gv[nt]     + bev[nt];
                    float zc = (acc[mt][nt + 4][rr] - mean) * inv * gv[nt + 4] + bev[nt + 4];
                    prod[mt * 16 + lg * 4 + rr][nt * 16 + lr] = sigmoidf_(zf) * softplusf_(zc);
                }
            }
        }
        __syncthreads();

        // epilogue: per-atom reduction over 12 rows + residual + softplus
        {
            int a_ = l >> 4;               // local atom 0..3
            int c0 = (l & 15) * 4;         // 4 consecutive channels
            float4 sm = make_float4(0, 0, 0, 0);
            #pragma unroll
            for (int m = 0; m < 12; ++m){
                const float4 pv = *(const float4*)&prod[a_ * 12 + m][c0];
                sm.x += pv.x; sm.y += pv.y; sm.z += pv.z; sm.w += pv.w;
            }
            int atom = blk * 4 + a_;
            float4 sf;
            if (layer == 0) sf = *(const float4*)(atom0F + (long)atom * 64 + c0);
            else            sf = *(const float4*)(&sSF[a_][c0]);
            float o0 = softplusf_(sf.x + sm.x);
            float o1 = softplusf_(sf.y + sm.y);
            float o2 = softplusf_(sf.z + sm.z);
            float o3 = softplusf_(sf.w + sm.w);
            if (layer == 0){
                *(float4*)(&sSF[a_][c0]) = make_float4(o0, o1, o2, o3);
                ushort4 hv;
                hv.x = f16bits((_Float16)o0); hv.y = f16bits((_Float16)o1);
                hv.z = f16bits((_Float16)o2); hv.w = f16bits((_Float16)o3);
                *(ushort4*)(&sSH[a_][c0]) = hv;
            } else {
                *(float4*)(outF + (long)atom * 64 + c0) = make_float4(o0, o1, o2, o3);
            }
        }
        __syncthreads();

        if (layer == 0){
            // self fragments for layer 2 from the LDS stash
            #pragma unroll
            for (int mt = 0; mt < 3; ++mt){
                int aloc = (mt * 16 + lr) / 12;
                #pragma unroll
                for (int c = 0; c < 2; ++c)
                    sfr[mt][c] = *(const f16x8*)(&sSH[aloc][c * 32 + lg * 8]);
            }
        }
    }
}

// ---------------- pooling: deterministic two-stage tree ----------------
__global__ __launch_bounds__(256) void k_partial(const float* __restrict__ atom,
        const float* __restrict__ occ, float* __restrict__ partials){
    int b = blockIdx.x, tid = threadIdx.x;
    int f = tid & 63, sub = tid >> 6;
    __shared__ float sAcc[256];
    float acc = 0.0f;
    for (int it = 0; it < 16; ++it){
        int a = b * 64 + sub + it * 4;
        float p = sigmoidf_(occ[a]);
        acc += atom[(long)a * FEA + f] * p;
    }
    sAcc[tid] = acc;
    __syncthreads();
    if (tid < 64){
        float s = sAcc[f] + sAcc[64 + f] + sAcc[128 + f] + sAcc[192 + f];
        partials[b * 65 + f] = s;
        float po = sigmoidf_(occ[b * 64 + f]);
        #pragma unroll
        for (int off = 32; off; off >>= 1) po += __shfl_down(po, off);
        if (f == 0) partials[b * 65 + 64] = po;
    }
}

__global__ __launch_bounds__(64) void k_final(const float* __restrict__ partials,
        const float* __restrict__ fc_w, const float* __restrict__ fc_b,
        float* __restrict__ out){
    int f = threadIdx.x;
    float num = 0.0f;
    for (int p = 0; p < 64; ++p) num += partials[p * 65 + f];
    float occs = partials[f * 65 + 64];
    #pragma unroll
    for (int off = 32; off; off >>= 1) occs += __shfl_down(occs, off);
    occs = __shfl(occs, 0);
    float gf = num / (occs + 1e-6f);
    float v = gf * fc_w[f];
    #pragma unroll
    for (int off = 32; off; off >>= 1) v += __shfl_down(v, off);
    if (f == 0) out[0] = v + fc_b[0];
}

extern "C" void kernel_launch(void* const* d_in, const int* in_sizes, int n_in,
                              void* d_out, int out_size, void* d_ws, size_t ws_size,
                              hipStream_t stream) {
    const float* lat    = (const float*)d_in[0];
    const float* fracs  = (const float*)d_in[1];
    const float* slog   = (const float*)d_in[2];
    const float* occ    = (const float*)d_in[3];
    const float* emb_w  = (const float*)d_in[4];
    const float* emb_b  = (const float*)d_in[5];
    const float* w1     = (const float*)d_in[6];
    const float* b1     = (const float*)d_in[7];
    const float* g1     = (const float*)d_in[8];
    const float* be1    = (const float*)d_in[9];
    const float* w2     = (const float*)d_in[10];
    const float* b2     = (const float*)d_in[11];
    const float* g2     = (const float*)d_in[12];
    const float* be2    = (const float*)d_in[13];
    const float* fc_w   = (const float*)d_in[14];
    const float* fc_b   = (const float*)d_in[15];
    float* out = (float*)d_out;

    char* ws = (char*)d_ws;
    auto alloc = [&](size_t bytes) -> void* {
        void* p = (void*)ws;
        ws += (bytes + 255) & ~(size_t)255;
        return p;
    };
    int*   nbr_idx  = (int*)  alloc((size_t)N_ATOMS * M_NBR * 4);
    float* nbr_dist = (float*)alloc((size_t)N_ATOMS * M_NBR * 4);
    float* atom0    = (float*)alloc((size_t)N_ATOMS * FEA * 4);
    float* atom1    = (float*)alloc((size_t)N_ATOMS * FEA * 4);
    u16*   a0f      = (u16*)  alloc((size_t)N_ATOMS * FEA * 2);
    u16*   w1f      = (u16*)  alloc((size_t)192 * 128 * 2);
    u16*   w2f      = (u16*)  alloc((size_t)192 * 128 * 2);
    float* fxa      = (float*)alloc((size_t)N_ATOMS * 4);
    float* fya      = (float*)alloc((size_t)N_ATOMS * 4);
    float* fza      = (float*)alloc((size_t)N_ATOMS * 4);
    float* partials = (float*)alloc((size_t)64 * 65 * 4);

    k_setup  <<<208, 256, 0, stream>>>(fracs, w1, w2, fxa, fya, fza, w1f, w2f);
    k_embed  <<<N_ATOMS / 4, 256, 0, stream>>>(slog, emb_w, emb_b, atom0, a0f);
    k_topk   <<<N_ATOMS, 256, 0, stream>>>(fxa, fya, fza, lat, nbr_idx, nbr_dist);
    k_fused  <<<N_ATOMS / 4, 64, 0, stream>>>(atom0, a0f, nbr_idx, nbr_dist,
                w1f, b1, g1, be1, w2f, b2, g2, be2, atom1);
    k_partial<<<64, 256, 0, stream>>>(atom1, occ, partials);
    k_final  <<<1, 64, 0, stream>>>(partials, fc_w, fc_b, out);
}

// Round 7
// 107.881 us; speedup vs baseline: 1.6646x; 1.0719x over previous
//
#include <hip/hip_runtime.h>
#include <math.h>

#define N_ATOMS 4096
#define SPECIES 100
#define FEA 64
#define M_NBR 12

typedef unsigned short u16;
typedef __attribute__((ext_vector_type(8))) _Float16 f16x8;
typedef __attribute__((ext_vector_type(4))) float f32x4;

constexpr float LN_EPS = 1e-5f;
constexpr float GAUSS_COEFF = -31.0078125f; // -0.5/(8/63)^2
constexpr float D2_INF = 3.4e38f;

__device__ __forceinline__ float sigmoidf_(float x){ return 1.0f/(1.0f+__expf(-x)); }
__device__ __forceinline__ float softplusf_(float x){
    return fmaxf(x, 0.0f) + log1pf(__expf(-fabsf(x)));
}
__device__ __forceinline__ u16 f16bits(_Float16 h){ return *(u16*)&h; }

// ---------------- setup: fracs transpose + weight fp16 split-pack ----------------
// W[192][128] splits into 3 K=64 blocks: self(0-63), nbr(64-127), gauss(128-191).
// mat = layer*3 + k/64  (0:S1 1:N1 2:G1 3:S2 4:N2 5:G2), each 16KB fp16 in
// per-(ch,nt) wave-contiguous B layout: dest[mat*8192 + ((ch*8+nt)*64+lane)*8 + i]
__global__ __launch_bounds__(256) void k_setup(const float* __restrict__ fracs,
        const float* __restrict__ w1, const float* __restrict__ w2,
        float* __restrict__ fx, float* __restrict__ fy, float* __restrict__ fz,
        u16* __restrict__ wpk){
    int b = blockIdx.x, t = threadIdx.x;
    if (b < 192){
        int gid = b * 256 + t;             // 0..49151
        int layer = gid / 24576;
        int e = gid % 24576;
        int k = e >> 7, n = e & 127;
        float x = (layer ? w2 : w1)[e];
        int mat = layer * 3 + (k >> 6);
        int kk = k & 63;
        int ch = kk >> 5, lg2 = (kk >> 3) & 3, i = kk & 7;
        int nt = n >> 4, lr2 = n & 15;
        int dest = mat * 8192 + ((ch * 8 + nt) * 64 + (lg2 * 16 + lr2)) * 8 + i;
        wpk[dest] = f16bits((_Float16)x);
    } else {
        int j = (b - 192) * 256 + t;
        fx[j] = fracs[j*3+0];
        fy[j] = fracs[j*3+1];
        fz[j] = fracs[j*3+2];
    }
}

// ---------------- embedding: softmax(species_logits) @ emb_w + emb_b ----------------
__global__ __launch_bounds__(256) void k_embed(const float* __restrict__ logits,
        const float* __restrict__ emb_w, const float* __restrict__ emb_b,
        float* __restrict__ atom0, u16* __restrict__ a0f){
    __shared__ float sE[4][SPECIES];
    int tid = threadIdx.x;
    int grp = tid >> 6;
    int f = tid & 63;
    int a = blockIdx.x * 4 + grp;
    const float* lg = logits + (long)a * SPECIES;
    float l0 = lg[f];
    float l1 = (f + 64 < SPECIES) ? lg[f + 64] : -1e30f;
    float mx = fmaxf(l0, l1);
    #pragma unroll
    for (int off = 32; off; off >>= 1) mx = fmaxf(mx, __shfl_xor(mx, off));
    float e0 = __expf(l0 - mx);
    float e1 = (f + 64 < SPECIES) ? __expf(l1 - mx) : 0.0f;
    sE[grp][f] = e0;
    if (f + 64 < SPECIES) sE[grp][64 + f] = e1;
    float sm = e0 + e1;
    #pragma unroll
    for (int off = 32; off; off >>= 1) sm += __shfl_xor(sm, off);
    __syncthreads();
    float acc = 0.0f;
    for (int s = 0; s < SPECIES; ++s) acc += sE[grp][s] * emb_w[s * FEA + f];
    float v = acc / sm + emb_b[f];
    atom0[(long)a * FEA + f] = v;
    a0f[a * FEA + f] = f16bits((_Float16)v);
}

// ---------------- top-12 via histogram threshold + candidate compaction ----------------
__global__ __launch_bounds__(256) void k_topk(const float* __restrict__ fx,
        const float* __restrict__ fy, const float* __restrict__ fz,
        const float* __restrict__ lat, int* __restrict__ nbr_idx,
        float* __restrict__ nbr_dist){
    __shared__ int   hist[256];
    __shared__ int   cnt;
    __shared__ float sThr;
    __shared__ float candD[256];
    __shared__ int   candI[256];
    int i = blockIdx.x, tid = threadIdx.x;
    hist[tid] = 0;
    if (tid == 0) cnt = 0;
    __syncthreads();
    float l00=lat[0],l01=lat[1],l02=lat[2];
    float l10=lat[3],l11=lat[4],l12=lat[5];
    float l20=lat[6],l21=lat[7],l22=lat[8];
    float xi = fx[i], yi = fy[i], zi = fz[i];
    float d2r[16];
    #pragma unroll
    for (int k = 0; k < 16; ++k){
        int j = tid + k * 256;
        float dx = xi - fx[j];
        float dy = yi - fy[j];
        float dz = zi - fz[j];
        dx -= rintf(dx); dy -= rintf(dy); dz -= rintf(dz);
        float cx = dx*l00 + dy*l10 + dz*l20;
        float cy = dx*l01 + dy*l11 + dz*l21;
        float cz = dx*l02 + dy*l12 + dz*l22;
        float d2 = cx*cx + cy*cy + cz*cz;
        if (j == i) d2 = D2_INF;
        d2r[k] = d2;
        if (d2 < 4.0f) atomicAdd(&hist[(int)(d2 * 64.0f)], 1);
    }
    __syncthreads();
    if (tid < 64){
        int s0 = hist[4*tid] + hist[4*tid+1] + hist[4*tid+2] + hist[4*tid+3];
        int sc = s0;
        #pragma unroll
        for (int off = 1; off < 64; off <<= 1){
            int o = __shfl_up(sc, off);
            if (tid >= off) sc += o;
        }
        unsigned long long mball = __ballot(sc >= M_NBR);
        if (mball == 0ULL){
            if (tid == 0) sThr = 1e30f;
        } else {
            int gbin = __ffsll(mball) - 1;
            if (tid == gbin){
                int c = sc - s0;
                float th = 4.0f;
                #pragma unroll
                for (int b = 0; b < 4; ++b){
                    c += hist[4*gbin + b];
                    if (c >= M_NBR){ th = (float)(4*gbin + b + 1) * (1.0f/64.0f); break; }
                }
                sThr = th;
            }
        }
    }
    __syncthreads();
    float thr = sThr;
    #pragma unroll
    for (int k = 0; k < 16; ++k){
        if (d2r[k] < thr){
            int p = atomicAdd(&cnt, 1);
            if (p < 256){ candD[p] = d2r[k]; candI[p] = tid + k * 256; }
        }
    }
    __syncthreads();
    if (tid < 64){
        int n = cnt < 256 ? cnt : 256;
        float v0 = (tid       < n) ? candD[tid]       : D2_INF;
        int   i0 = (tid       < n) ? candI[tid]       : 0x7FFFFFFF;
        float v1 = (tid + 64  < n) ? candD[tid + 64]  : D2_INF;
        int   i1 = (tid + 64  < n) ? candI[tid + 64]  : 0x7FFFFFFF;
        float v2 = (tid + 128 < n) ? candD[tid + 128] : D2_INF;
        int   i2 = (tid + 128 < n) ? candI[tid + 128] : 0x7FFFFFFF;
        float v3 = (tid + 192 < n) ? candD[tid + 192] : D2_INF;
        int   i3 = (tid + 192 < n) ? candI[tid + 192] : 0x7FFFFFFF;
        for (int r = 0; r < M_NBR; ++r){
            float bv = v0; int bi = i0;
            if (v1 < bv || (v1 == bv && i1 < bi)){ bv = v1; bi = i1; }
            if (v2 < bv || (v2 == bv && i2 < bi)){ bv = v2; bi = i2; }
            if (v3 < bv || (v3 == bv && i3 < bi)){ bv = v3; bi = i3; }
            #pragma unroll
            for (int off = 1; off < 64; off <<= 1){
                float ov = __shfl_xor(bv, off);
                int   oi = __shfl_xor(bi, off);
                if (ov < bv || (ov == bv && oi < bi)){ bv = ov; bi = oi; }
            }
            if (i0 == bi) v0 = D2_INF;
            if (i1 == bi) v1 = D2_INF;
            if (i2 == bi) v2 = D2_INF;
            if (i3 == bi) v3 = D2_INF;
            if (tid == 0){
                nbr_idx[i * M_NBR + r]  = bi;
                nbr_dist[i * M_NBR + r] = sqrtf(bv);
            }
        }
    }
}

// ---------------- precompute S1 = a0@Ws1, N1 = a0@Wn1, N2 = a0@Wn2 ----------------
// [4096 x 64] @ [64 x 128] each; one wave = 16 rows; grid 256.
__global__ __launch_bounds__(64) void k_precomp(const u16* __restrict__ a0f,
        const u16* __restrict__ wpk, float* __restrict__ S1,
        float* __restrict__ N1, float* __restrict__ N2){
    const int l = threadIdx.x;
    const int lg = l >> 4, lr = l & 15;
    const int blk = blockIdx.x;
    f16x8 af[2];
    #pragma unroll
    for (int c = 0; c < 2; ++c)
        af[c] = *(const f16x8*)(a0f + (blk * 16 + lr) * 64 + c * 32 + lg * 8);
    const u16* WB[3] = { wpk, wpk + 8192, wpk + 4 * 8192 };   // S1, N1, N2
    float* OUT[3] = { S1, N1, N2 };
    #pragma unroll
    for (int m = 0; m < 3; ++m){
        f32x4 acc[8];
        #pragma unroll
        for (int nt = 0; nt < 8; ++nt) acc[nt] = 0.0f;
        #pragma unroll
        for (int c = 0; c < 2; ++c)
            #pragma unroll
            for (int nt = 0; nt < 8; ++nt){
                const f16x8 b = *(const f16x8*)(WB[m] + ((c * 8 + nt) * 64 + l) * 8);
                acc[nt] = __builtin_amdgcn_mfma_f32_16x16x32_f16(af[c], b, acc[nt], 0, 0, 0);
            }
        #pragma unroll
        for (int nt = 0; nt < 8; ++nt)
            #pragma unroll
            for (int rr = 0; rr < 4; ++rr)
                OUT[m][(blk * 16 + lg * 4 + rr) * 128 + nt * 16 + lr] = acc[nt][rr];
    }
}

// ---------------- fused CGCNN layers 1+2 (gaussian-GEMM only; S/N gathered) --------
// Block = 192 threads (3 waves x 16 rows) = 48 rows = 4 atoms; grid 1024 (12 waves/CU).
__global__ __launch_bounds__(192) void k_fused(
        const float* __restrict__ atom0F,
        const int* __restrict__ nbr_idx, const float* __restrict__ nbr_dist,
        const float* __restrict__ S1g, const float* __restrict__ N1g,
        const float* __restrict__ N2g, const u16* __restrict__ wpk,
        const float* __restrict__ b1, const float* __restrict__ g1, const float* __restrict__ be1,
        const float* __restrict__ b2, const float* __restrict__ g2, const float* __restrict__ be2,
        float* __restrict__ outF)
{
    __shared__ float prod[48][68];   // 13.1KB
    __shared__ float sSF[4][64];     // layer-1 out f32 (residual for layer 2)
    __shared__ u16   sSH[4][64];     // layer-1 out fp16 (A-frags for S2 mini-GEMM)
    __shared__ float sS2[4][132];    // S2 = atom1 @ Ws2 (padded rows)
    const int t = threadIdx.x;
    const int w = t >> 6, l = t & 63;
    const int lg = l >> 4, lr = l & 15;
    const int blk = blockIdx.x;
    const int rbase = blk * 48 + w * 16;

    const u16* wg1 = wpk + 2 * 8192;
    const u16* ws2 = wpk + 3 * 8192;
    const u16* wg2 = wpk + 5 * 8192;

    // gaussian A-fragments (A-layout row = lr), shared by both layers: 16 exps/lane
    const float dist = nbr_dist[rbase + lr];
    f16x8 ga[2];
    #pragma unroll
    for (int c = 0; c < 2; ++c)
        #pragma unroll
        for (int i = 0; i < 8; ++i){
            int k = c * 32 + lg * 8 + i;
            float dd = dist - (float)k * (8.0f / 63.0f);
            ga[c][i] = (_Float16)__expf(GAUSS_COEFF * dd * dd);
        }

    // z-row mapping (C-layout rows: lg*4+rr)
    int znid[4], zaid[4];
    #pragma unroll
    for (int rr = 0; rr < 4; ++rr){
        int zr = rbase + lg * 4 + rr;
        znid[rr] = nbr_idx[zr];
        zaid[rr] = zr / 12;
    }

    // ================= layer 1 =================
    {
        f32x4 acc[8];
        #pragma unroll
        for (int nt = 0; nt < 8; ++nt) acc[nt] = 0.0f;
        #pragma unroll
        for (int c = 0; c < 2; ++c)
            #pragma unroll
            for (int nt = 0; nt < 8; ++nt){
                const f16x8 b = *(const f16x8*)(wg1 + ((c * 8 + nt) * 64 + l) * 8);
                acc[nt] = __builtin_amdgcn_mfma_f32_16x16x32_f16(ga[c], b, acc[nt], 0, 0, 0);
            }
        float z[8][4];
        float s[4] = {0,0,0,0}, q[4] = {0,0,0,0};
        #pragma unroll
        for (int nt = 0; nt < 8; ++nt){
            int c = nt * 16 + lr;
            float bb = b1[c];
            #pragma unroll
            for (int rr = 0; rr < 4; ++rr){
                float v = acc[nt][rr] + S1g[zaid[rr] * 128 + c] + N1g[znid[rr] * 128 + c] + bb;
                z[nt][rr] = v; s[rr] += v; q[rr] += v * v;
            }
        }
        #pragma unroll
        for (int rr = 0; rr < 4; ++rr){
            #pragma unroll
            for (int m = 1; m < 16; m <<= 1){
                s[rr] += __shfl_xor(s[rr], m);
                q[rr] += __shfl_xor(q[rr], m);
            }
        }
        #pragma unroll
        for (int rr = 0; rr < 4; ++rr){
            float mean = s[rr] * (1.0f / 128.0f);
            float var  = q[rr] * (1.0f / 128.0f) - mean * mean;
            float inv  = rsqrtf(var + LN_EPS);
            #pragma unroll
            for (int nt = 0; nt < 4; ++nt){
                int cf = nt * 16 + lr, cc = cf + 64;
                float zf = (z[nt][rr]     - mean) * inv * g1[cf] + be1[cf];
                float zc = (z[nt + 4][rr] - mean) * inv * g1[cc] + be1[cc];
                prod[w * 16 + lg * 4 + rr][cf] = sigmoidf_(zf) * softplusf_(zc);
            }
        }
    }
    __syncthreads();

    // epilogue 1: per-atom reduce 12 rows + residual + softplus -> sSF/sSH
    if (t < 64){
        int a_ = t >> 4, c0 = (t & 15) * 4;
        float4 sm = make_float4(0, 0, 0, 0);
        #pragma unroll
        for (int m = 0; m < 12; ++m){
            const float4 pv = *(const float4*)&prod[a_ * 12 + m][c0];
            sm.x += pv.x; sm.y += pv.y; sm.z += pv.z; sm.w += pv.w;
        }
        int atom = blk * 4 + a_;
        const float4 sf = *(const float4*)(atom0F + (long)atom * 64 + c0);
        float o0 = softplusf_(sf.x + sm.x);
        float o1 = softplusf_(sf.y + sm.y);
        float o2 = softplusf_(sf.z + sm.z);
        float o3 = softplusf_(sf.w + sm.w);
        *(float4*)(&sSF[a_][c0]) = make_float4(o0, o1, o2, o3);
        ushort4 hv;
        hv.x = f16bits((_Float16)o0); hv.y = f16bits((_Float16)o1);
        hv.z = f16bits((_Float16)o2); hv.w = f16bits((_Float16)o3);
        *(ushort4*)(&sSH[a_][c0]) = hv;
    }
    __syncthreads();

    // S2 mini-GEMM (wave 0): S2[a][c] = atom1[a][:] @ Ws2, a = 0..3
    if (t < 64){
        f16x8 af[2];
        #pragma unroll
        for (int c = 0; c < 2; ++c){
            if (lr < 4) af[c] = *(const f16x8*)(&sSH[lr][c * 32 + lg * 8]);
            else        af[c] = 0;
        }
        f32x4 a2[8];
        #pragma unroll
        for (int nt = 0; nt < 8; ++nt) a2[nt] = 0.0f;
        #pragma unroll
        for (int c = 0; c < 2; ++c)
            #pragma unroll
            for (int nt = 0; nt < 8; ++nt){
                const f16x8 b = *(const f16x8*)(ws2 + ((c * 8 + nt) * 64 + l) * 8);
                a2[nt] = __builtin_amdgcn_mfma_f32_16x16x32_f16(af[c], b, a2[nt], 0, 0, 0);
            }
        if (lg == 0){
            #pragma unroll
            for (int nt = 0; nt < 8; ++nt)
                #pragma unroll
                for (int rr = 0; rr < 4; ++rr)
                    sS2[rr][nt * 16 + lr] = a2[nt][rr];
        }
    }
    __syncthreads();

    // ================= layer 2 =================
    {
        f32x4 acc[8];
        #pragma unroll
        for (int nt = 0; nt < 8; ++nt) acc[nt] = 0.0f;
        #pragma unroll
        for (int c = 0; c < 2; ++c)
            #pragma unroll
            for (int nt = 0; nt < 8; ++nt){
                const f16x8 b = *(const f16x8*)(wg2 + ((c * 8 + nt) * 64 + l) * 8);
                acc[nt] = __builtin_amdgcn_mfma_f32_16x16x32_f16(ga[c], b, acc[nt], 0, 0, 0);
            }
        float z[8][4];
        float s[4] = {0,0,0,0}, q[4] = {0,0,0,0};
        #pragma unroll
        for (int nt = 0; nt < 8; ++nt){
            int c = nt * 16 + lr;
            float bb = b2[c];
            #pragma unroll
            for (int rr = 0; rr < 4; ++rr){
                int aloc = zaid[rr] - blk * 4;
                float v = acc[nt][rr] + sS2[aloc][c] + N2g[znid[rr] * 128 + c] + bb;
                z[nt][rr] = v; s[rr] += v; q[rr] += v * v;
            }
        }
        #pragma unroll
        for (int rr = 0; rr < 4; ++rr){
            #pragma unroll
            for (int m = 1; m < 16; m <<= 1){
                s[rr] += __shfl_xor(s[rr], m);
                q[rr] += __shfl_xor(q[rr], m);
            }
        }
        #pragma unroll
        for (int rr = 0; rr < 4; ++rr){
            float mean = s[rr] * (1.0f / 128.0f);
            float var  = q[rr] * (1.0f / 128.0f) - mean * mean;
            float inv  = rsqrtf(var + LN_EPS);
            #pragma unroll
            for (int nt = 0; nt < 4; ++nt){
                int cf = nt * 16 + lr, cc = cf + 64;
                float zf = (z[nt][rr]     - mean) * inv * g2[cf] + be2[cf];
                float zc = (z[nt + 4][rr] - mean) * inv * g2[cc] + be2[cc];
                prod[w * 16 + lg * 4 + rr][cf] = sigmoidf_(zf) * softplusf_(zc);
            }
        }
    }
    __syncthreads();

    // epilogue 2 -> outF
    if (t < 64){
        int a_ = t >> 4, c0 = (t & 15) * 4;
        float4 sm = make_float4(0, 0, 0, 0);
        #pragma unroll
        for (int m = 0; m < 12; ++m){
            const float4 pv = *(const float4*)&prod[a_ * 12 + m][c0];
            sm.x += pv.x; sm.y += pv.y; sm.z += pv.z; sm.w += pv.w;
        }
        int atom = blk * 4 + a_;
        const float4 sf = *(const float4*)(&sSF[a_][c0]);
        float o0 = softplusf_(sf.x + sm.x);
        float o1 = softplusf_(sf.y + sm.y);
        float o2 = softplusf_(sf.z + sm.z);
        float o3 = softplusf_(sf.w + sm.w);
        *(float4*)(outF + (long)atom * 64 + c0) = make_float4(o0, o1, o2, o3);
    }
}

// ---------------- pooling: deterministic two-stage tree ----------------
__global__ __launch_bounds__(256) void k_partial(const float* __restrict__ atom,
        const float* __restrict__ occ, float* __restrict__ partials){
    int b = blockIdx.x, tid = threadIdx.x;
    int f = tid & 63, sub = tid >> 6;
    __shared__ float sAcc[256];
    float acc = 0.0f;
    for (int it = 0; it < 16; ++it){
        int a = b * 64 + sub + it * 4;
        float p = sigmoidf_(occ[a]);
        acc += atom[(long)a * FEA + f] * p;
    }
    sAcc[tid] = acc;
    __syncthreads();
    if (tid < 64){
        float s = sAcc[f] + sAcc[64 + f] + sAcc[128 + f] + sAcc[192 + f];
        partials[b * 65 + f] = s;
        float po = sigmoidf_(occ[b * 64 + f]);
        #pragma unroll
        for (int off = 32; off; off >>= 1) po += __shfl_down(po, off);
        if (f == 0) partials[b * 65 + 64] = po;
    }
}

__global__ __launch_bounds__(64) void k_final(const float* __restrict__ partials,
        const float* __restrict__ fc_w, const float* __restrict__ fc_b,
        float* __restrict__ out){
    int f = threadIdx.x;
    float num = 0.0f;
    for (int p = 0; p < 64; ++p) num += partials[p * 65 + f];
    float occs = partials[f * 65 + 64];
    #pragma unroll
    for (int off = 32; off; off >>= 1) occs += __shfl_down(occs, off);
    occs = __shfl(occs, 0);
    float gf = num / (occs + 1e-6f);
    float v = gf * fc_w[f];
    #pragma unroll
    for (int off = 32; off; off >>= 1) v += __shfl_down(v, off);
    if (f == 0) out[0] = v + fc_b[0];
}

extern "C" void kernel_launch(void* const* d_in, const int* in_sizes, int n_in,
                              void* d_out, int out_size, void* d_ws, size_t ws_size,
                              hipStream_t stream) {
    const float* lat    = (const float*)d_in[0];
    const float* fracs  = (const float*)d_in[1];
    const float* slog   = (const float*)d_in[2];
    const float* occ    = (const float*)d_in[3];
    const float* emb_w  = (const float*)d_in[4];
    const float* emb_b  = (const float*)d_in[5];
    const float* w1     = (const float*)d_in[6];
    const float* b1     = (const float*)d_in[7];
    const float* g1     = (const float*)d_in[8];
    const float* be1    = (const float*)d_in[9];
    const float* w2     = (const float*)d_in[10];
    const float* b2     = (const float*)d_in[11];
    const float* g2     = (const float*)d_in[12];
    const float* be2    = (const float*)d_in[13];
    const float* fc_w   = (const float*)d_in[14];
    const float* fc_b   = (const float*)d_in[15];
    float* out = (float*)d_out;

    char* ws = (char*)d_ws;
    auto alloc = [&](size_t bytes) -> void* {
        void* p = (void*)ws;
        ws += (bytes + 255) & ~(size_t)255;
        return p;
    };
    int*   nbr_idx  = (int*)  alloc((size_t)N_ATOMS * M_NBR * 4);
    float* nbr_dist = (float*)alloc((size_t)N_ATOMS * M_NBR * 4);
    float* atom0    = (float*)alloc((size_t)N_ATOMS * FEA * 4);
    float* atom1    = (float*)alloc((size_t)N_ATOMS * FEA * 4);
    u16*   a0f      = (u16*)  alloc((size_t)N_ATOMS * FEA * 2);
    u16*   wpk      = (u16*)  alloc((size_t)6 * 8192 * 2);
    float* S1       = (float*)alloc((size_t)N_ATOMS * 128 * 4);
    float* N1       = (float*)alloc((size_t)N_ATOMS * 128 * 4);
    float* N2       = (float*)alloc((size_t)N_ATOMS * 128 * 4);
    float* fxa      = (float*)alloc((size_t)N_ATOMS * 4);
    float* fya      = (float*)alloc((size_t)N_ATOMS * 4);
    float* fza      = (float*)alloc((size_t)N_ATOMS * 4);
    float* partials = (float*)alloc((size_t)64 * 65 * 4);

    k_setup  <<<208, 256, 0, stream>>>(fracs, w1, w2, fxa, fya, fza, wpk);
    k_embed  <<<N_ATOMS / 4, 256, 0, stream>>>(slog, emb_w, emb_b, atom0, a0f);
    k_topk   <<<N_ATOMS, 256, 0, stream>>>(fxa, fya, fza, lat, nbr_idx, nbr_dist);
    k_precomp<<<N_ATOMS / 16, 64, 0, stream>>>(a0f, wpk, S1, N1, N2);
    k_fused  <<<N_ATOMS / 4, 192, 0, stream>>>(atom0, nbr_idx, nbr_dist, S1, N1, N2,
                wpk, b1, g1, be1, b2, g2, be2, atom1);
    k_partial<<<64, 256, 0, stream>>>(atom1, occ, partials);
    k_final  <<<1, 64, 0, stream>>>(partials, fc_w, fc_b, out);
}